// Round 19
// baseline (112.792 us; speedup 1.0000x reference)
//
#include <hip/hip_runtime.h>
#include <math.h>

namespace {

typedef __attribute__((ext_vector_type(8))) short short8;
typedef __attribute__((ext_vector_type(4))) float f32x4;

constexpr int NL  = 1024;
constexpr int ND  = 512;
constexpr int NH  = 8;
constexpr int NV3 = 36;
constexpr int NCAT = 2560;   // packed projection output cols (2448 used)
constexpr int KF   = 832;    // final-GEMM K (824 used)

constexpr float SCL_S = 0.044194173824159216f; // 1/sqrt(512)
constexpr float SCL_V = 1.0f / 6.0f;           // 1/sqrt(36)
constexpr float FIXM  = 12.0f;                 // fixed softmax max (logits ~ +-6)

__device__ inline ushort f2bf(float f) {
  uint u = __float_as_uint(f);
  u += 0x7FFFu + ((u >> 16) & 1u);
  return (ushort)(u >> 16);
}
__device__ inline float bf2f(ushort h) { return __uint_as_float((uint)h << 16); }

#define MFMA(a, b, c) __builtin_amdgcn_mfma_f32_16x16x32_bf16((a), (b), (c), 0, 0, 0)

// ---------------------------------------------------------------- k_wprep
__global__ __launch_bounds__(256) void k_wprep(
    const float* __restrict__ wq, const float* __restrict__ wk,
    const float* __restrict__ wv, const float* __restrict__ wvq,
    const float* __restrict__ wvk, const float* __restrict__ wvv,
    const float* __restrict__ waq, const float* __restrict__ wav,
    const float* __restrict__ w_o, const float* __restrict__ w_vo,
    const float* __restrict__ w_ao, const float* __restrict__ x,
    ushort* __restrict__ wch, ushort* __restrict__ wcat2,
    ushort* __restrict__ xh, ushort* __restrict__ xl)
{
  __shared__ float t[64][65];
  const int tid = threadIdx.x;
  const int z = blockIdx.z;
  if (z == 2) {
    const int bid = blockIdx.y * 40 + blockIdx.x;
    if (bid >= 512) return;
    const size_t i = ((size_t)bid * 256 + tid) * 8;
#pragma unroll
    for (int q = 0; q < 2; ++q) {
      const float4 v = *(const float4*)&x[i + q * 4];
      ushort4 h, l;
      h.x = f2bf(v.x); l.x = f2bf(v.x - bf2f(h.x));
      h.y = f2bf(v.y); l.y = f2bf(v.y - bf2f(h.y));
      h.z = f2bf(v.z); l.z = f2bf(v.z - bf2f(h.z));
      h.w = f2bf(v.w); l.w = f2bf(v.w - bf2f(h.w));
      *(ushort4*)&xh[i + q * 4] = h;
      *(ushort4*)&xl[i + q * 4] = l;
    }
    return;
  }
  if (z == 0) { if (blockIdx.y >= 8) return; }
  else        { if (blockIdx.x >= 8) return; }
  const int n0 = blockIdx.x * 64, k0 = blockIdx.y * 64;
  const int rr = tid >> 6, cc = tid & 63;

  for (int p = 0; p < 16; ++p) {
    const int kk = k0 + p * 4 + rr;
    const int nn = n0 + cc;
    float val;
    if (z == 0) {
      if (nn < 1536) {
        const float* w = nn < 512 ? wq : (nn < 1024 ? wk : wv);
        val = w[(size_t)kk * 512 + (nn & 511)];
      } else if (nn < 2400) {
        const float* w = nn < 1824 ? wvq : (nn < 2112 ? wvk : wvv);
        val = w[(size_t)kk * 288 + (nn - 1536) % 288];
      } else if (nn < 2424) val = waq[(size_t)kk * 24 + nn - 2400];
      else if (nn < 2448)   val = wav[(size_t)kk * 24 + nn - 2424];
      else val = 0.f;
    } else {
      if (kk < 512)      val = w_o [(size_t)kk * 512 + nn];
      else if (kk < 800) val = w_vo[(size_t)(kk - 512) * 512 + nn];
      else if (kk < 824) val = w_ao[(size_t)(kk - 800) * 512 + nn];
      else val = 0.f;
    }
    t[p * 4 + rr][cc] = val;
  }
  __syncthreads();
  for (int p = 0; p < 16; ++p) {
    const int nn = p * 4 + rr;
    const int kk = cc;
    const float val = t[kk][nn];
    if (z == 0) wch[(size_t)(n0 + nn) * 512 + k0 + kk] = f2bf(val);
    else        wcat2[(size_t)(n0 + nn) * 832 + k0 + kk] = f2bf(val);
  }
}

// ---------------------------------------------------------------- k_mm
__global__ __launch_bounds__(256) void k_mm(
    const ushort* __restrict__ Ah, const ushort* __restrict__ Al,
    const ushort* __restrict__ Bh,
    float* __restrict__ Y, int N, int K)
{
  __shared__ __align__(16) ushort Ahs[128][40];
  __shared__ __align__(16) ushort Als[128][40];
  __shared__ __align__(16) ushort Bhs[64][40];
  const int tid = threadIdx.x;
  const int m0 = blockIdx.x * 128, n0 = blockIdx.y * 64;
  const int w = tid >> 6, lane = tid & 63;
  const int wm = (w & 1) * 64, wn = (w >> 1) * 32;
  const int fr = lane & 15, fg = lane >> 4;

  f32x4 acc[4][2];
#pragma unroll
  for (int i = 0; i < 4; ++i)
#pragma unroll
    for (int j = 0; j < 2; ++j) acc[i][j] = (f32x4){0.f, 0.f, 0.f, 0.f};

  const int ar = tid >> 1, ak = (tid & 1) * 16;
  const int br = tid >> 2, bk = (tid & 3) * 8;
  const ushort* agh = Ah + (size_t)(m0 + ar) * K + ak;
  const ushort* agl = Al + (size_t)(m0 + ar) * K + ak;
  const ushort* bgh = Bh + (size_t)(n0 + br) * K + bk;
  short8 pah0 = *(const short8*)agh, pah1 = *(const short8*)(agh + 8);
  short8 pal0 = *(const short8*)agl, pal1 = *(const short8*)(agl + 8);
  short8 pbh0 = *(const short8*)bgh;

  const int NT = K >> 5;
  for (int kt = 0; kt < NT; ++kt) {
    __syncthreads();
    *(short8*)&Ahs[ar][ak] = pah0; *(short8*)&Ahs[ar][ak + 8] = pah1;
    *(short8*)&Als[ar][ak] = pal0; *(short8*)&Als[ar][ak + 8] = pal1;
    *(short8*)&Bhs[br][bk] = pbh0;
    __syncthreads();
    if (kt + 1 < NT) {
      const size_t off = (size_t)(kt + 1) * 32;
      pah0 = *(const short8*)(agh + off); pah1 = *(const short8*)(agh + off + 8);
      pal0 = *(const short8*)(agl + off); pal1 = *(const short8*)(agl + off + 8);
      pbh0 = *(const short8*)(bgh + off);
    }
    short8 fah[4], fal[4], fbh[2];
#pragma unroll
    for (int i = 0; i < 4; ++i) {
      fah[i] = *(const short8*)&Ahs[wm + i * 16 + fr][fg * 8];
      fal[i] = *(const short8*)&Als[wm + i * 16 + fr][fg * 8];
    }
#pragma unroll
    for (int j = 0; j < 2; ++j)
      fbh[j] = *(const short8*)&Bhs[wn + j * 16 + fr][fg * 8];
#pragma unroll
    for (int i = 0; i < 4; ++i)
#pragma unroll
      for (int j = 0; j < 2; ++j) {
        f32x4 t = MFMA(fah[i], fbh[j], acc[i][j]);
        acc[i][j] = MFMA(fal[i], fbh[j], t);
      }
  }

  const int rb = fg * 4;
#pragma unroll
  for (int i = 0; i < 4; ++i)
#pragma unroll
    for (int j = 0; j < 2; ++j) {
      const int n = n0 + wn + j * 16 + fr;
#pragma unroll
      for (int r = 0; r < 4; ++r) {
        const int m = m0 + wm + i * 16 + rb + r;
        Y[(size_t)m * N + n] = acc[i][j][r];
      }
    }
}

// ---------------------------------------------------------------- k_fin
__global__ __launch_bounds__(256) void k_fin(
    const ushort* __restrict__ A, const ushort* __restrict__ Bt,
    const float* __restrict__ b_vo, const float* __restrict__ b_ao,
    float* __restrict__ out)
{
  __shared__ __align__(16) ushort As[64][40];
  __shared__ __align__(16) ushort Bs[64][40];
  const int tid = threadIdx.x;
  const int m0 = blockIdx.x * 64, n0 = blockIdx.y * 64;
  const int w = tid >> 6, lane = tid & 63;
  const int wm = (w & 1) * 32, wn = (w >> 1) * 32;
  const int fr = lane & 15, fg = lane >> 4;
  const int K = KF;

  f32x4 acc[2][2];
#pragma unroll
  for (int i = 0; i < 2; ++i)
#pragma unroll
    for (int j = 0; j < 2; ++j) acc[i][j] = (f32x4){0.f, 0.f, 0.f, 0.f};

  const int ar = tid >> 2, ak = (tid & 3) * 8;
  const ushort* ag = A + (size_t)(m0 + ar) * K + ak;
  const ushort* bg = Bt + (size_t)(n0 + ar) * K + ak;
  short8 a0 = *(const short8*)ag;
  short8 b0 = *(const short8*)bg;

  const int NT = K >> 5;
  for (int kt = 0; kt < NT; ++kt) {
    __syncthreads();
    *(short8*)&As[ar][ak] = a0;
    *(short8*)&Bs[ar][ak] = b0;
    __syncthreads();
    if (kt + 1 < NT) {
      const size_t off = (size_t)(kt + 1) * 32;
      a0 = *(const short8*)(ag + off);
      b0 = *(const short8*)(bg + off);
    }
    short8 aF[2], bF[2];
#pragma unroll
    for (int i = 0; i < 2; ++i) aF[i] = *(const short8*)&As[wm + i * 16 + fr][fg * 8];
#pragma unroll
    for (int j = 0; j < 2; ++j) bF[j] = *(const short8*)&Bs[wn + j * 16 + fr][fg * 8];
#pragma unroll
    for (int i = 0; i < 2; ++i)
#pragma unroll
      for (int j = 0; j < 2; ++j)
        acc[i][j] = MFMA(aF[i], bF[j], acc[i][j]);
  }

  const int rb = fg * 4;
#pragma unroll
  for (int j = 0; j < 2; ++j) {
    const int n = n0 + wn + j * 16 + fr;
    const float bias = b_vo[n] + b_ao[n];
#pragma unroll
    for (int i = 0; i < 2; ++i)
#pragma unroll
      for (int r = 0; r < 4; ++r) {
        const int m = m0 + wm + i * 16 + rb + r;
        out[(size_t)m * ND + n] = acc[i][j][r] + bias;
      }
  }
}

// ---------------------------------------------------------------- k_stage
__global__ __launch_bounds__(256) void k_stage(
    const float* __restrict__ Y,
    const float* __restrict__ rots, const float* __restrict__ trans,
    const float* __restrict__ mask,
    const float* __restrict__ bvq, const float* __restrict__ bvk,
    const float* __restrict__ bvv, const float* __restrict__ baq,
    const float* __restrict__ bav,
    ushort* __restrict__ qAh, ushort* __restrict__ kBh,
    ushort* __restrict__ Vt,
    float* __restrict__ aq_t, float* __restrict__ penc)
{
  __shared__ __align__(16) char sbuf[36864];
  const int tid = threadIdx.x;

  if (blockIdx.z == 0) {
    float (*t0)[65] = (float(*)[65])sbuf;
    float (*t1)[72] = (float(*)[72])(sbuf + 16640);
    const int l0 = blockIdx.x * 64, h = blockIdx.y;
    const int b = l0 >> 10, ll0 = l0 & 1023;
    const int bh = b * NH + h;
    const int rr = tid >> 6, cc = tid & 63;
    const float inv = powf(10000.f, -(float)(cc & ~1) / 64.f);
    const bool odd = (cc & 1) != 0;

    for (int p = 0; p < 16; ++p) {
      const int r = p * 4 + rr;
      t0[r][cc] = Y[(size_t)(l0 + r) * NCAT + h * 64 + cc];
    }
    __syncthreads();
    for (int p = 0; p < 16; ++p) {
      const int r = p * 4 + rr;
      float sv, cv;
      __sincosf((float)(ll0 + r) * inv, &sv, &cv);
      const float e = t0[r][cc & ~1], o = t0[r][(cc & ~1) + 1];
      const float val = (odd ? fmaf(e, sv, o * cv) : fmaf(e, cv, -o * sv)) * SCL_S;
      qAh[((size_t)bh * NL + ll0 + r) * 128 + cc] = f2bf(val);
    }
    __syncthreads();
    for (int p = 0; p < 16; ++p) {
      const int r = p * 4 + rr;
      t0[r][cc] = Y[(size_t)(l0 + r) * NCAT + 512 + h * 64 + cc];
    }
    __syncthreads();
    for (int p = 0; p < 16; ++p) {
      const int r = p * 4 + rr;
      float sv, cv;
      __sincosf((float)(ll0 + r) * inv, &sv, &cv);
      const float e = t0[r][cc & ~1], o = t0[r][(cc & ~1) + 1];
      const float val = odd ? fmaf(e, sv, o * cv) : fmaf(e, cv, -o * sv);
      kBh[((size_t)bh * NL + ll0 + r) * 128 + cc] = f2bf(val);
    }
    for (int p = 0; p < 16; ++p) {
      const int r = p * 4 + rr;
      t1[cc][r] = Y[(size_t)(l0 + r) * NCAT + 1024 + h * 64 + cc];
    }
    __syncthreads();
    for (int p = 0; p < 16; ++p) {
      const int hd = p * 4 + rr;
      Vt[((size_t)bh * 112 + hd) * NL + ll0 + cc] = f2bf(t1[hd][cc]);
    }
    for (int u = tid; u < 9 * 64; u += 256)
      Vt[((size_t)bh * 112 + 103 + (u >> 6)) * NL + ll0 + (u & 63)] = 0;
    return;
  }

  float (*ys)[912] = (float(*)[912])sbuf;
  const int bid = blockIdx.y * 32 + blockIdx.x;
  const int tb = bid * 8;
  const int b = tb >> 10;

  for (int t = 0; t < 8; ++t)
    for (int n = tid; n < 912; n += 256)
      ys[t][n] = Y[(size_t)(tb + t) * NCAT + 1536 + n];
  __syncthreads();

  for (int u = tid; u < 8 * 288; u += 256) {
    const int t = u / 288, n = u % 288;
    const int l = tb + t, ll = l & (NL - 1);
    const int c = n % 3, base = n - c;
    const int h = n / NV3, m = n % NV3;
    const float r0 = rots[(size_t)l * 9 + c * 3 + 0];
    const float r1 = rots[(size_t)l * 9 + c * 3 + 1];
    const float r2 = rots[(size_t)l * 9 + c * 3 + 2];
    const float vqv = (r0 * (ys[t][base] + bvq[base])
                     + r1 * (ys[t][base + 1] + bvq[base + 1])
                     + r2 * (ys[t][base + 2] + bvq[base + 2])) * SCL_V;
    const float vkv = r0 * (ys[t][288 + base] + bvk[base])
                    + r1 * (ys[t][289 + base] + bvk[base + 1])
                    + r2 * (ys[t][290 + base] + bvk[base + 2]);
    const float vvv = r0 * (ys[t][576 + base] + bvv[base])
                    + r1 * (ys[t][577 + base] + bvv[base + 1])
                    + r2 * (ys[t][578 + base] + bvv[base + 2]);
    const size_t row = ((size_t)(b * NH + h) * NL + ll) * 128 + 64 + m;
    qAh[row] = f2bf(vqv);
    kBh[row] = f2bf(vkv);
    Vt[((size_t)(b * NH + h) * 112 + 64 + m) * NL + ll] = f2bf(vvv);
  }
  for (int u = tid; u < 8 * 8 * 14; u += 256) {
    const int t = u / 112, rem = u % 112, h = rem / 14, k = rem % 14;
    const int ll = (tb + t) & (NL - 1);
    const size_t row = ((size_t)(b * NH + h) * NL + ll) * 128 + 100 + 2 * k;
    *(uint*)&qAh[row] = 0;
  }
  for (int u = tid; u < 64; u += 256) {
    const int t = u >> 3, h = u & 7;
    const int l = tb + t, ll = l & (NL - 1);
    const int base = h * 3;
    const size_t tok = (size_t)(b * NH + h) * NL + ll;
#pragma unroll
    for (int c = 0; c < 3; ++c) {
      const float aqv =
          rots[(size_t)l * 9 + c * 3 + 0] * (ys[t][864 + base] + baq[base])
        + rots[(size_t)l * 9 + c * 3 + 1] * (ys[t][865 + base] + baq[base + 1])
        + rots[(size_t)l * 9 + c * 3 + 2] * (ys[t][866 + base] + baq[base + 2])
        + trans[(size_t)l * 3 + c];
      aq_t[((size_t)(b * NH + h) * 3 + c) * NL + ll] = aqv;
    }
#pragma unroll
    for (int k = 0; k < 14; ++k)
      *(uint*)&kBh[tok * 128 + 100 + 2 * k] = 0;
  }
  for (int u = tid; u < 8 * 24; u += 256) {
    const int t = u / 24, n = u % 24;
    const int l = tb + t, ll = l & (NL - 1);
    const int c = n % 3, h = n / 3, base = h * 3;
    const float val = rots[(size_t)l * 9 + c * 3 + 0] * (ys[t][888 + base] + bav[base])
                    + rots[(size_t)l * 9 + c * 3 + 1] * (ys[t][889 + base] + bav[base + 1])
                    + rots[(size_t)l * 9 + c * 3 + 2] * (ys[t][890 + base] + bav[base + 2])
                    + trans[(size_t)l * 3 + c];
    Vt[((size_t)(b * NH + h) * 112 + 100 + c) * NL + ll] = f2bf(val);
  }
  for (int u = tid; u < 8; u += 256) {
    const int ll = (tb + u) & (NL - 1);
    penc[(size_t)b * NL + ll] = 1e6f * (1.0f - mask[(size_t)b * NL + ll]);
  }
}

// ---------------------------------------------------------------- k_attn
// 16-wave cooperative flash attention: 1024 thr = 4 row-groups x 4
// j-quarters, 64 q-rows/block. Per iteration stage all 4 quarters'
// 64-wide K tiles + aq/pen (FIXM folded); V read direct from L2.
// Fixed-max softmax -> cross-wave combine is plain 4-way sum.
// Grid 256 = 16 bh x 4 row-tiles (64 rows), XCD-swizzled; 16 waves/CU.
__global__ __launch_bounds__(1024) void k_attn(
    const ushort* __restrict__ qAh,
    const ushort* __restrict__ kBh, const ushort* __restrict__ Vt,
    const float* __restrict__ aq_t, const float* __restrict__ penc,
    const float* __restrict__ rots, const float* __restrict__ trans,
    const float* __restrict__ affw,
    ushort* __restrict__ catb)
{
  __shared__ __align__(16) ushort Ks[4][64][136];  // 69632 B
  __shared__ float Aqs[4][4][64];                  // 4096 B
  __shared__ __align__(16) ushort P_s[16][16][72]; // 36864 B
  __shared__ float lst[16][16];
  __shared__ float linv[4][16];
  // Opart (epilogue) overlays Ks: 16*16*112*2 = 57344 <= 69632
  ushort (*Opart)[16][112] = (ushort(*)[16][112])&Ks[0][0][0];

  const int blk = blockIdx.x;
  const int bh  = (blk & 7) * 2 + (blk >> 7);
  const int i0  = ((blk >> 3) & 15) * 64;
  const int b = bh >> 3, h = bh & 7;
  const int tid = threadIdx.x;
  const int w = tid >> 6, lane = tid & 63;
  const int rg = w & 3, jq = w >> 2;
  const int fr = lane & 15, fg = lane >> 4;
  const int irow = i0 + rg * 16;

  const float spw = logf(1.0f + expf(affw[h]));

  short8 aQ[4];
  const size_t qrow = ((size_t)bh * NL + irow + fr) * 128;
#pragma unroll
  for (int ks = 0; ks < 4; ++ks)
    aQ[ks] = *(const short8*)&qAh[qrow + ks * 32 + fg * 8];

  const float* aqx = aq_t + (size_t)bh * 3 * NL;
  float ai0[4], ai1[4], ai2[4];
#pragma unroll
  for (int r_ = 0; r_ < 4; ++r_) {
    const int row = irow + fg * 4 + r_;
    ai0[r_] = aqx[row];
    ai1[r_] = aqx[NL + row];
    ai2[r_] = aqx[2 * NL + row];
  }

  float lsum[4] = {0.f, 0.f, 0.f, 0.f};
  f32x4 accO[7];
#pragma unroll
  for (int ct = 0; ct < 7; ++ct) accO[ct] = (f32x4){0.f, 0.f, 0.f, 0.f};

  const size_t vbase = (size_t)bh * 112 * NL;

  // staging roles: K = 4 quarters x 64 rows x 128 cols; 1 thread = 32 cols.
  const int kq = tid >> 8, krow = (tid >> 2) & 63, kc0 = (tid & 3) * 32;
  const size_t kgb = (size_t)bh * NL * 128
                   + (size_t)(kq * 256 + krow) * 128 + kc0;
  // aq/pen: 1 value/thread: [quarter][comp][col]
  const int aqq = tid >> 8, aqc = (tid >> 6) & 3, aqj = tid & 63;

  short8 kp[4];
  float ap;

  auto loadTile = [&](int t) {
#pragma unroll
    for (int k = 0; k < 4; ++k)
      kp[k] = *(const short8*)&kBh[kgb + (size_t)t * 64 * 128 + k * 8];
    const int j = aqq * 256 + t * 64 + aqj;
    ap = (aqc < 3) ? aqx[aqc * NL + j]
                   : penc[(size_t)b * NL + j] + FIXM;
  };
  auto storeTile = [&]() {
#pragma unroll
    for (int k = 0; k < 4; ++k)
      *(short8*)&Ks[kq][krow][kc0 + k * 8] = kp[k];
    Aqs[aqq][aqc][aqj] = ap;
  };

  loadTile(0);
  for (int t = 0; t < 4; ++t) {
    __syncthreads();
    storeTile();
    __syncthreads();
    if (t < 3) loadTile(t + 1);

    const int j0 = jq * 256 + t * 64;

    // QK from staged K (this wave's quarter)
    f32x4 accS[4];
#pragma unroll
    for (int ct = 0; ct < 4; ++ct) accS[ct] = (f32x4){0.f, 0.f, 0.f, 0.f};
#pragma unroll
    for (int ct = 0; ct < 4; ++ct) {
#pragma unroll
      for (int ks = 0; ks < 4; ++ks) {
        const short8 bh8 = *(const short8*)&Ks[jq][ct * 16 + fr][ks * 32 + fg * 8];
        accS[ct] = MFMA(aQ[ks], bh8, accS[ct]);
      }
    }

    // distances + folded penalty; P = exp(s - penF)
#pragma unroll
    for (int ct = 0; ct < 4; ++ct) {
      const int jj = ct * 16 + fr;
      const float aj0 = Aqs[jq][0][jj];
      const float aj1 = Aqs[jq][1][jj];
      const float aj2v = Aqs[jq][2][jj];
      const float penF = Aqs[jq][3][jj];
#pragma unroll
      for (int r_ = 0; r_ < 4; ++r_) {
        const float dx = ai0[r_] - aj0;
        const float dy = ai1[r_] - aj1;
        const float dz = ai2[r_] - aj2v;
        const float s = accS[ct][r_]
                      - spw * sqrtf(dx * dx + dy * dy + dz * dz) - penF;
        const float p = __expf(s);
        accS[ct][r_] = p;
        lsum[r_] += p;
      }
    }

    // P tile (wave-private LDS)
#pragma unroll
    for (int ct = 0; ct < 4; ++ct)
#pragma unroll
      for (int r_ = 0; r_ < 4; ++r_)
        P_s[w][fg * 4 + r_][ct * 16 + fr] = f2bf(accS[ct][r_]);

    const short8 aP0 = *(const short8*)&P_s[w][fr][fg * 8];
    const short8 aP1 = *(const short8*)&P_s[w][fr][32 + fg * 8];
#pragma unroll
    for (int ct = 0; ct < 7; ++ct) {
      const size_t vrow = vbase + (size_t)(ct * 16 + fr) * NL + j0;
      const short8 b0 = *(const short8*)&Vt[vrow + fg * 8];
      const short8 b1 = *(const short8*)&Vt[vrow + 32 + fg * 8];
      f32x4 tacc = MFMA(aP0, b0, accO[ct]);
      accO[ct] = MFMA(aP1, b1, tacc);
    }
  }

  // reduce L across fr lanes
#pragma unroll
  for (int off = 1; off < 16; off <<= 1) {
#pragma unroll
    for (int r_ = 0; r_ < 4; ++r_) lsum[r_] += __shfl_xor(lsum[r_], off);
  }

  __syncthreads();   // all QK reads of Ks done before Opart overlays it

  // publish partials (bf16 O, fp32 L)
#pragma unroll
  for (int ct = 0; ct < 7; ++ct)
#pragma unroll
    for (int r_ = 0; r_ < 4; ++r_)
      Opart[w][fg * 4 + r_][ct * 16 + fr] = f2bf(accO[ct][r_]);
  if (fr == 0) {
#pragma unroll
    for (int r_ = 0; r_ < 4; ++r_) lst[w][fg * 4 + r_] = lsum[r_];
  }
  __syncthreads();

  if (tid < 64) {
    const int g = tid >> 4, row = tid & 15;
    linv[g][row] = 1.0f / (lst[g][row] + lst[4 + g][row]
                         + lst[8 + g][row] + lst[12 + g][row]);
  }
  __syncthreads();

  // epilogue: sum-combine j-quarters + rotations + catb writes
  auto comb = [&](int row, int d) -> float {
    const int g = row >> 4, r16 = row & 15;
    return (bf2f(Opart[g][r16][d]) + bf2f(Opart[4 + g][r16][d])
          + bf2f(Opart[8 + g][r16][d]) + bf2f(Opart[12 + g][r16][d]))
         * linv[g][r16];
  };
  for (int u = tid; u < 64 * 103; u += 1024) {
    const int lr = u / 103, d = u % 103;
    const int gi = i0 + lr;
    const size_t gl = (size_t)b * NL + gi;
    float val;
    int col;
    if (d < 64) {
      val = comb(lr, d);
      col = h * 64 + d;
    } else if (d < 100) {
      const int v3 = d - 64;
      const int n = v3 % 3;
      const int base = 64 + v3 - n;
      val = comb(lr, base)     * rots[gl * 9 + n]
          + comb(lr, base + 1) * rots[gl * 9 + 3 + n]
          + comb(lr, base + 2) * rots[gl * 9 + 6 + n];
      col = 512 + h * NV3 + v3;
    } else {
      const int n = d - 100;
      const float c0 = comb(lr, 100) - trans[gl * 3 + 0];
      const float c1 = comb(lr, 101) - trans[gl * 3 + 1];
      const float c2 = comb(lr, 102) - trans[gl * 3 + 2];
      val = c0 * rots[gl * 9 + n] + c1 * rots[gl * 9 + 3 + n] + c2 * rots[gl * 9 + 6 + n];
      col = 800 + h * 3 + n;
    }
    catb[gl * KF + col] = f2bf(val);
  }
  if (h == 0) {
    for (int u = tid; u < 64 * 8; u += 1024)
      catb[((size_t)b * NL + i0 + (u >> 3)) * KF + 824 + (u & 7)] = 0;
  }
}

} // namespace

extern "C" void kernel_launch(void* const* d_in, const int* in_sizes, int n_in,
                              void* d_out, int out_size, void* d_ws, size_t ws_size,
                              hipStream_t stream)
{
  const float* x       = (const float*)d_in[0];
  const float* mask    = (const float*)d_in[1];
  const float* rots    = (const float*)d_in[2];
  const float* trans   = (const float*)d_in[3];
  const float* w_q     = (const float*)d_in[4];
  const float* w_k     = (const float*)d_in[5];
  const float* w_v     = (const float*)d_in[6];
  const float* w_o     = (const float*)d_in[7];
  const float* w_vq_w  = (const float*)d_in[8];
  const float* w_vq_b  = (const float*)d_in[9];
  const float* w_vk_w  = (const float*)d_in[10];
  const float* w_vk_b  = (const float*)d_in[11];
  const float* w_vv_w  = (const float*)d_in[12];
  const float* w_vv_b  = (const float*)d_in[13];
  const float* w_vo_w  = (const float*)d_in[14];
  const float* w_vo_b  = (const float*)d_in[15];
  const float* w_aq_w  = (const float*)d_in[16];
  const float* w_aq_b  = (const float*)d_in[17];
  const float* w_av_w  = (const float*)d_in[18];
  const float* w_av_b  = (const float*)d_in[19];
  const float* w_ao_w  = (const float*)d_in[20];
  const float* w_ao_b  = (const float*)d_in[21];
  const float* aff_w   = (const float*)d_in[22];
  float* out = (float*)d_out;

  char* base = (char*)d_ws;
  ushort* xh  = (ushort*)base;
  ushort* xl  = xh + (size_t)2048 * 512;
  ushort* wch = xl + (size_t)2048 * 512;
  ushort* qAh = (ushort*)base;                       // 4 MB (over xh+xl)
  float*  aq_t = (float*)(wch + (size_t)2560 * 512); // 196 KB (after wch)
  char* p = base + 9437184;
  ushort* wcat2 = (ushort*)p; p += (size_t)512 * 832 * 2;
  float*  Y     = (float*)p;
  ushort* catb  = (ushort*)Y;
  p += (size_t)2048 * 2560 * 4;
  ushort* kBh = (ushort*)p; p += (size_t)16 * 1024 * 128 * 2;
  ushort* Vt  = (ushort*)p; p += (size_t)16 * 112 * 1024 * 2;
  float* penc = (float*)p;  p += (size_t)2048 * 4;

  k_wprep<<<dim3(40, 13, 3), 256, 0, stream>>>(w_q, w_k, w_v, w_vq_w, w_vk_w,
                                               w_vv_w, w_aq_w, w_av_w,
                                               w_o, w_vo_w, w_ao_w, x,
                                               wch, wcat2, xh, xl);
  k_mm<<<dim3(16, 40), 256, 0, stream>>>(xh, xl, wch, Y, NCAT, 512);
  k_stage<<<dim3(32, 8, 2), 256, 0, stream>>>(Y, rots, trans, mask,
                                              w_vq_b, w_vk_b, w_vv_b,
                                              w_aq_b, w_av_b,
                                              qAh, kBh, Vt, aq_t, penc);
  k_attn<<<256, 1024, 0, stream>>>(qAh, kBh, Vt,
                                   aq_t, penc, rots, trans, aff_w, catb);
  k_fin<<<dim3(32, 8), 256, 0, stream>>>(catb, wcat2, w_vo_b, w_ao_b, out);
}

// Round 20
// 109.463 us; speedup vs baseline: 1.0304x; 1.0304x over previous
//
#include <hip/hip_runtime.h>
#include <math.h>

namespace {

typedef __attribute__((ext_vector_type(8))) short short8;
typedef __attribute__((ext_vector_type(4))) float f32x4;

constexpr int NL  = 1024;
constexpr int ND  = 512;
constexpr int NH  = 8;
constexpr int NV3 = 36;
constexpr int NCAT = 2560;   // packed projection output cols (2448 used)
constexpr int KF   = 832;    // final-GEMM K (824 used)

constexpr float SCL_S = 0.044194173824159216f; // 1/sqrt(512)
constexpr float SCL_V = 1.0f / 6.0f;           // 1/sqrt(36)
constexpr float FIXM  = 12.0f;                 // fixed softmax max (logits ~ +-6)

__device__ inline ushort f2bf(float f) {
  uint u = __float_as_uint(f);
  u += 0x7FFFu + ((u >> 16) & 1u);
  return (ushort)(u >> 16);
}
__device__ inline float bf2f(ushort h) { return __uint_as_float((uint)h << 16); }

#define MFMA(a, b, c) __builtin_amdgcn_mfma_f32_16x16x32_bf16((a), (b), (c), 0, 0, 0)

// ---------------------------------------------------------------- k_wprep
__global__ __launch_bounds__(256) void k_wprep(
    const float* __restrict__ wq, const float* __restrict__ wk,
    const float* __restrict__ wv, const float* __restrict__ wvq,
    const float* __restrict__ wvk, const float* __restrict__ wvv,
    const float* __restrict__ waq, const float* __restrict__ wav,
    const float* __restrict__ w_o, const float* __restrict__ w_vo,
    const float* __restrict__ w_ao, const float* __restrict__ x,
    ushort* __restrict__ wch, ushort* __restrict__ wcat2,
    ushort* __restrict__ xh, ushort* __restrict__ xl)
{
  __shared__ float t[64][65];
  const int tid = threadIdx.x;
  const int z = blockIdx.z;
  if (z == 2) {
    const int bid = blockIdx.y * 40 + blockIdx.x;
    if (bid >= 512) return;
    const size_t i = ((size_t)bid * 256 + tid) * 8;
#pragma unroll
    for (int q = 0; q < 2; ++q) {
      const float4 v = *(const float4*)&x[i + q * 4];
      ushort4 h, l;
      h.x = f2bf(v.x); l.x = f2bf(v.x - bf2f(h.x));
      h.y = f2bf(v.y); l.y = f2bf(v.y - bf2f(h.y));
      h.z = f2bf(v.z); l.z = f2bf(v.z - bf2f(h.z));
      h.w = f2bf(v.w); l.w = f2bf(v.w - bf2f(h.w));
      *(ushort4*)&xh[i + q * 4] = h;
      *(ushort4*)&xl[i + q * 4] = l;
    }
    return;
  }
  if (z == 0) { if (blockIdx.y >= 8) return; }
  else        { if (blockIdx.x >= 8) return; }
  const int n0 = blockIdx.x * 64, k0 = blockIdx.y * 64;
  const int rr = tid >> 6, cc = tid & 63;

  for (int p = 0; p < 16; ++p) {
    const int kk = k0 + p * 4 + rr;
    const int nn = n0 + cc;
    float val;
    if (z == 0) {
      if (nn < 1536) {
        const float* w = nn < 512 ? wq : (nn < 1024 ? wk : wv);
        val = w[(size_t)kk * 512 + (nn & 511)];
      } else if (nn < 2400) {
        const float* w = nn < 1824 ? wvq : (nn < 2112 ? wvk : wvv);
        val = w[(size_t)kk * 288 + (nn - 1536) % 288];
      } else if (nn < 2424) val = waq[(size_t)kk * 24 + nn - 2400];
      else if (nn < 2448)   val = wav[(size_t)kk * 24 + nn - 2424];
      else val = 0.f;
    } else {
      if (kk < 512)      val = w_o [(size_t)kk * 512 + nn];
      else if (kk < 800) val = w_vo[(size_t)(kk - 512) * 512 + nn];
      else if (kk < 824) val = w_ao[(size_t)(kk - 800) * 512 + nn];
      else val = 0.f;
    }
    t[p * 4 + rr][cc] = val;
  }
  __syncthreads();
  for (int p = 0; p < 16; ++p) {
    const int nn = p * 4 + rr;
    const int kk = cc;
    const float val = t[kk][nn];
    if (z == 0) wch[(size_t)(n0 + nn) * 512 + k0 + kk] = f2bf(val);
    else        wcat2[(size_t)(n0 + nn) * 832 + k0 + kk] = f2bf(val);
  }
}

// ---------------------------------------------------------------- k_mm
__global__ __launch_bounds__(256) void k_mm(
    const ushort* __restrict__ Ah, const ushort* __restrict__ Al,
    const ushort* __restrict__ Bh,
    float* __restrict__ Y, int N, int K)
{
  __shared__ __align__(16) ushort Ahs[128][40];
  __shared__ __align__(16) ushort Als[128][40];
  __shared__ __align__(16) ushort Bhs[64][40];
  const int tid = threadIdx.x;
  const int m0 = blockIdx.x * 128, n0 = blockIdx.y * 64;
  const int w = tid >> 6, lane = tid & 63;
  const int wm = (w & 1) * 64, wn = (w >> 1) * 32;
  const int fr = lane & 15, fg = lane >> 4;

  f32x4 acc[4][2];
#pragma unroll
  for (int i = 0; i < 4; ++i)
#pragma unroll
    for (int j = 0; j < 2; ++j) acc[i][j] = (f32x4){0.f, 0.f, 0.f, 0.f};

  const int ar = tid >> 1, ak = (tid & 1) * 16;
  const int br = tid >> 2, bk = (tid & 3) * 8;
  const ushort* agh = Ah + (size_t)(m0 + ar) * K + ak;
  const ushort* agl = Al + (size_t)(m0 + ar) * K + ak;
  const ushort* bgh = Bh + (size_t)(n0 + br) * K + bk;
  short8 pah0 = *(const short8*)agh, pah1 = *(const short8*)(agh + 8);
  short8 pal0 = *(const short8*)agl, pal1 = *(const short8*)(agl + 8);
  short8 pbh0 = *(const short8*)bgh;

  const int NT = K >> 5;
  for (int kt = 0; kt < NT; ++kt) {
    __syncthreads();
    *(short8*)&Ahs[ar][ak] = pah0; *(short8*)&Ahs[ar][ak + 8] = pah1;
    *(short8*)&Als[ar][ak] = pal0; *(short8*)&Als[ar][ak + 8] = pal1;
    *(short8*)&Bhs[br][bk] = pbh0;
    __syncthreads();
    if (kt + 1 < NT) {
      const size_t off = (size_t)(kt + 1) * 32;
      pah0 = *(const short8*)(agh + off); pah1 = *(const short8*)(agh + off + 8);
      pal0 = *(const short8*)(agl + off); pal1 = *(const short8*)(agl + off + 8);
      pbh0 = *(const short8*)(bgh + off);
    }
    short8 fah[4], fal[4], fbh[2];
#pragma unroll
    for (int i = 0; i < 4; ++i) {
      fah[i] = *(const short8*)&Ahs[wm + i * 16 + fr][fg * 8];
      fal[i] = *(const short8*)&Als[wm + i * 16 + fr][fg * 8];
    }
#pragma unroll
    for (int j = 0; j < 2; ++j)
      fbh[j] = *(const short8*)&Bhs[wn + j * 16 + fr][fg * 8];
#pragma unroll
    for (int i = 0; i < 4; ++i)
#pragma unroll
      for (int j = 0; j < 2; ++j) {
        f32x4 t = MFMA(fah[i], fbh[j], acc[i][j]);
        acc[i][j] = MFMA(fal[i], fbh[j], t);
      }
  }

  const int rb = fg * 4;
#pragma unroll
  for (int i = 0; i < 4; ++i)
#pragma unroll
    for (int j = 0; j < 2; ++j) {
      const int n = n0 + wn + j * 16 + fr;
#pragma unroll
      for (int r = 0; r < 4; ++r) {
        const int m = m0 + wm + i * 16 + rb + r;
        Y[(size_t)m * N + n] = acc[i][j][r];
      }
    }
}

// ---------------------------------------------------------------- k_fin
__global__ __launch_bounds__(256) void k_fin(
    const ushort* __restrict__ A, const ushort* __restrict__ Bt,
    const float* __restrict__ b_vo, const float* __restrict__ b_ao,
    float* __restrict__ out)
{
  __shared__ __align__(16) ushort As[64][40];
  __shared__ __align__(16) ushort Bs[64][40];
  const int tid = threadIdx.x;
  const int m0 = blockIdx.x * 64, n0 = blockIdx.y * 64;
  const int w = tid >> 6, lane = tid & 63;
  const int wm = (w & 1) * 32, wn = (w >> 1) * 32;
  const int fr = lane & 15, fg = lane >> 4;
  const int K = KF;

  f32x4 acc[2][2];
#pragma unroll
  for (int i = 0; i < 2; ++i)
#pragma unroll
    for (int j = 0; j < 2; ++j) acc[i][j] = (f32x4){0.f, 0.f, 0.f, 0.f};

  const int ar = tid >> 2, ak = (tid & 3) * 8;
  const ushort* ag = A + (size_t)(m0 + ar) * K + ak;
  const ushort* bg = Bt + (size_t)(n0 + ar) * K + ak;
  short8 a0 = *(const short8*)ag;
  short8 b0 = *(const short8*)bg;

  const int NT = K >> 5;
  for (int kt = 0; kt < NT; ++kt) {
    __syncthreads();
    *(short8*)&As[ar][ak] = a0;
    *(short8*)&Bs[ar][ak] = b0;
    __syncthreads();
    if (kt + 1 < NT) {
      const size_t off = (size_t)(kt + 1) * 32;
      a0 = *(const short8*)(ag + off);
      b0 = *(const short8*)(bg + off);
    }
    short8 aF[2], bF[2];
#pragma unroll
    for (int i = 0; i < 2; ++i) aF[i] = *(const short8*)&As[wm + i * 16 + fr][fg * 8];
#pragma unroll
    for (int j = 0; j < 2; ++j) bF[j] = *(const short8*)&Bs[wn + j * 16 + fr][fg * 8];
#pragma unroll
    for (int i = 0; i < 2; ++i)
#pragma unroll
      for (int j = 0; j < 2; ++j)
        acc[i][j] = MFMA(aF[i], bF[j], acc[i][j]);
  }

  const int rb = fg * 4;
#pragma unroll
  for (int j = 0; j < 2; ++j) {
    const int n = n0 + wn + j * 16 + fr;
    const float bias = b_vo[n] + b_ao[n];
#pragma unroll
    for (int i = 0; i < 2; ++i)
#pragma unroll
      for (int r = 0; r < 4; ++r) {
        const int m = m0 + wm + i * 16 + rb + r;
        out[(size_t)m * ND + n] = acc[i][j][r] + bias;
      }
  }
}

// ---------------------------------------------------------------- k_stage
__global__ __launch_bounds__(256) void k_stage(
    const float* __restrict__ Y,
    const float* __restrict__ rots, const float* __restrict__ trans,
    const float* __restrict__ mask,
    const float* __restrict__ bvq, const float* __restrict__ bvk,
    const float* __restrict__ bvv, const float* __restrict__ baq,
    const float* __restrict__ bav,
    ushort* __restrict__ qAh, ushort* __restrict__ kBh,
    ushort* __restrict__ Vt,
    float* __restrict__ aq_t, float* __restrict__ penc)
{
  __shared__ __align__(16) char sbuf[36864];
  const int tid = threadIdx.x;

  if (blockIdx.z == 0) {
    float (*t0)[65] = (float(*)[65])sbuf;
    float (*t1)[72] = (float(*)[72])(sbuf + 16640);
    const int l0 = blockIdx.x * 64, h = blockIdx.y;
    const int b = l0 >> 10, ll0 = l0 & 1023;
    const int bh = b * NH + h;
    const int rr = tid >> 6, cc = tid & 63;
    const float inv = powf(10000.f, -(float)(cc & ~1) / 64.f);
    const bool odd = (cc & 1) != 0;

    for (int p = 0; p < 16; ++p) {
      const int r = p * 4 + rr;
      t0[r][cc] = Y[(size_t)(l0 + r) * NCAT + h * 64 + cc];
    }
    __syncthreads();
    for (int p = 0; p < 16; ++p) {
      const int r = p * 4 + rr;
      float sv, cv;
      __sincosf((float)(ll0 + r) * inv, &sv, &cv);
      const float e = t0[r][cc & ~1], o = t0[r][(cc & ~1) + 1];
      const float val = (odd ? fmaf(e, sv, o * cv) : fmaf(e, cv, -o * sv)) * SCL_S;
      qAh[((size_t)bh * NL + ll0 + r) * 128 + cc] = f2bf(val);
    }
    __syncthreads();
    for (int p = 0; p < 16; ++p) {
      const int r = p * 4 + rr;
      t0[r][cc] = Y[(size_t)(l0 + r) * NCAT + 512 + h * 64 + cc];
    }
    __syncthreads();
    for (int p = 0; p < 16; ++p) {
      const int r = p * 4 + rr;
      float sv, cv;
      __sincosf((float)(ll0 + r) * inv, &sv, &cv);
      const float e = t0[r][cc & ~1], o = t0[r][(cc & ~1) + 1];
      const float val = odd ? fmaf(e, sv, o * cv) : fmaf(e, cv, -o * sv);
      kBh[((size_t)bh * NL + ll0 + r) * 128 + cc] = f2bf(val);
    }
    for (int p = 0; p < 16; ++p) {
      const int r = p * 4 + rr;
      t1[cc][r] = Y[(size_t)(l0 + r) * NCAT + 1024 + h * 64 + cc];
    }
    __syncthreads();
    for (int p = 0; p < 16; ++p) {
      const int hd = p * 4 + rr;
      Vt[((size_t)bh * 112 + hd) * NL + ll0 + cc] = f2bf(t1[hd][cc]);
    }
    for (int u = tid; u < 9 * 64; u += 256)
      Vt[((size_t)bh * 112 + 103 + (u >> 6)) * NL + ll0 + (u & 63)] = 0;
    return;
  }

  float (*ys)[912] = (float(*)[912])sbuf;
  const int bid = blockIdx.y * 32 + blockIdx.x;
  const int tb = bid * 8;
  const int b = tb >> 10;

  for (int t = 0; t < 8; ++t)
    for (int n = tid; n < 912; n += 256)
      ys[t][n] = Y[(size_t)(tb + t) * NCAT + 1536 + n];
  __syncthreads();

  for (int u = tid; u < 8 * 288; u += 256) {
    const int t = u / 288, n = u % 288;
    const int l = tb + t, ll = l & (NL - 1);
    const int c = n % 3, base = n - c;
    const int h = n / NV3, m = n % NV3;
    const float r0 = rots[(size_t)l * 9 + c * 3 + 0];
    const float r1 = rots[(size_t)l * 9 + c * 3 + 1];
    const float r2 = rots[(size_t)l * 9 + c * 3 + 2];
    const float vqv = (r0 * (ys[t][base] + bvq[base])
                     + r1 * (ys[t][base + 1] + bvq[base + 1])
                     + r2 * (ys[t][base + 2] + bvq[base + 2])) * SCL_V;
    const float vkv = r0 * (ys[t][288 + base] + bvk[base])
                    + r1 * (ys[t][289 + base] + bvk[base + 1])
                    + r2 * (ys[t][290 + base] + bvk[base + 2]);
    const float vvv = r0 * (ys[t][576 + base] + bvv[base])
                    + r1 * (ys[t][577 + base] + bvv[base + 1])
                    + r2 * (ys[t][578 + base] + bvv[base + 2]);
    const size_t row = ((size_t)(b * NH + h) * NL + ll) * 128 + 64 + m;
    qAh[row] = f2bf(vqv);
    kBh[row] = f2bf(vkv);
    Vt[((size_t)(b * NH + h) * 112 + 64 + m) * NL + ll] = f2bf(vvv);
  }
  for (int u = tid; u < 8 * 8 * 14; u += 256) {
    const int t = u / 112, rem = u % 112, h = rem / 14, k = rem % 14;
    const int ll = (tb + t) & (NL - 1);
    const size_t row = ((size_t)(b * NH + h) * NL + ll) * 128 + 100 + 2 * k;
    *(uint*)&qAh[row] = 0;
  }
  for (int u = tid; u < 64; u += 256) {
    const int t = u >> 3, h = u & 7;
    const int l = tb + t, ll = l & (NL - 1);
    const int base = h * 3;
    const size_t tok = (size_t)(b * NH + h) * NL + ll;
#pragma unroll
    for (int c = 0; c < 3; ++c) {
      const float aqv =
          rots[(size_t)l * 9 + c * 3 + 0] * (ys[t][864 + base] + baq[base])
        + rots[(size_t)l * 9 + c * 3 + 1] * (ys[t][865 + base] + baq[base + 1])
        + rots[(size_t)l * 9 + c * 3 + 2] * (ys[t][866 + base] + baq[base + 2])
        + trans[(size_t)l * 3 + c];
      aq_t[((size_t)(b * NH + h) * 3 + c) * NL + ll] = aqv;
    }
#pragma unroll
    for (int k = 0; k < 14; ++k)
      *(uint*)&kBh[tok * 128 + 100 + 2 * k] = 0;
  }
  for (int u = tid; u < 8 * 24; u += 256) {
    const int t = u / 24, n = u % 24;
    const int l = tb + t, ll = l & (NL - 1);
    const int c = n % 3, h = n / 3, base = h * 3;
    const float val = rots[(size_t)l * 9 + c * 3 + 0] * (ys[t][888 + base] + bav[base])
                    + rots[(size_t)l * 9 + c * 3 + 1] * (ys[t][889 + base] + bav[base + 1])
                    + rots[(size_t)l * 9 + c * 3 + 2] * (ys[t][890 + base] + bav[base + 2])
                    + trans[(size_t)l * 3 + c];
    Vt[((size_t)(b * NH + h) * 112 + 100 + c) * NL + ll] = f2bf(val);
  }
  for (int u = tid; u < 8; u += 256) {
    const int ll = (tb + u) & (NL - 1);
    penc[(size_t)b * NL + ll] = 1e6f * (1.0f - mask[(size_t)b * NL + ll]);
  }
}

// ---------------------------------------------------------------- k_attn
// (round-18 proven structure + FIXM folded into staged penalty)
// 8-wave cooperative flash attention: 512 thr = 4 row-groups x 2 j-halves.
// Each iteration stages BOTH halves' 64-wide K/V/aq tiles; wave (rg,jh)
// computes its half. Fixed-max softmax -> cross-wave combine is plain sum.
// Grid 256 = 16 bh x 16 row-tiles (64 rows), XCD-swizzled; 8 waves/CU.
__global__ __launch_bounds__(512) void k_attn(
    const ushort* __restrict__ qAh,
    const ushort* __restrict__ kBh, const ushort* __restrict__ Vt,
    const float* __restrict__ aq_t, const float* __restrict__ penc,
    const float* __restrict__ rots, const float* __restrict__ trans,
    const float* __restrict__ affw,
    ushort* __restrict__ catb)
{
  __shared__ __align__(16) ushort Ks[2][64][136];
  __shared__ __align__(16) ushort Vs[2][112][72];
  __shared__ float Aqs[2][4][64];
  __shared__ __align__(16) char uni[28672];   // P_s (loop) / Opart (epilogue)
  __shared__ float lst[8][16];
  __shared__ float linv[4][16];

  ushort (*P_s)[16][72]   = (ushort(*)[16][72])uni;
  ushort (*Opart)[16][112] = (ushort(*)[16][112])uni;

  const int blk = blockIdx.x;
  const int bh  = (blk & 7) * 2 + (blk >> 7);
  const int i0  = ((blk >> 3) & 15) * 64;
  const int b = bh >> 3, h = bh & 7;
  const int tid = threadIdx.x;
  const int w = tid >> 6, lane = tid & 63;
  const int rg = w & 3, jh = w >> 2;
  const int fr = lane & 15, fg = lane >> 4;
  const int irow = i0 + rg * 16;

  const float spw = logf(1.0f + expf(affw[h]));

  short8 aQ[4];
  const size_t qrow = ((size_t)bh * NL + irow + fr) * 128;
#pragma unroll
  for (int ks = 0; ks < 4; ++ks)
    aQ[ks] = *(const short8*)&qAh[qrow + ks * 32 + fg * 8];

  const float* aqx = aq_t + (size_t)bh * 3 * NL;
  float ai0[4], ai1[4], ai2[4];
#pragma unroll
  for (int r_ = 0; r_ < 4; ++r_) {
    const int row = irow + fg * 4 + r_;
    ai0[r_] = aqx[row];
    ai1[r_] = aqx[NL + row];
    ai2[r_] = aqx[2 * NL + row];
  }

  float lsum[4] = {0.f, 0.f, 0.f, 0.f};
  f32x4 accO[7];
#pragma unroll
  for (int ct = 0; ct < 7; ++ct) accO[ct] = (f32x4){0.f, 0.f, 0.f, 0.f};

  // staging roles (512 threads stage 2 half-tiles per iteration)
  const int hk = tid >> 8, krow = (tid >> 2) & 63, kc0 = (tid & 3) * 32;
  const int hv = (tid < 448) ? tid / 224 : 0;
  const int vrem = (tid < 448) ? tid % 224 : 0;
  const int vrow = vrem >> 1, vc0 = (vrem & 1) * 32;
  const int au = tid - 448;                      // tid>=448: aq/pen (64 thr)
  const size_t kgb = (size_t)bh * NL * 128 + (size_t)(hk * 512 + krow) * 128 + kc0;
  const size_t vgb = ((size_t)bh * 112 + vrow) * NL + hv * 512 + vc0;

  short8 kp[4], vp[4];
  float ap[8];

  auto loadTile = [&](int t) {
#pragma unroll
    for (int k = 0; k < 4; ++k)
      kp[k] = *(const short8*)&kBh[kgb + (size_t)t * 64 * 128 + k * 8];
    if (tid < 448) {
#pragma unroll
      for (int k = 0; k < 4; ++k)
        vp[k] = *(const short8*)&Vt[vgb + t * 64 + k * 8];
    } else {
#pragma unroll
      for (int q = 0; q < 8; ++q) {
        const int idx = au * 8 + q;              // 0..511
        const int ha = idx >> 8, rem2 = idx & 255;
        const int c = rem2 >> 6, jj = rem2 & 63;
        const int j = ha * 512 + t * 64 + jj;
        ap[q] = (c < 3) ? aqx[c * NL + j]
                        : penc[(size_t)b * NL + j] + FIXM;
      }
    }
  };
  auto storeTile = [&]() {
#pragma unroll
    for (int k = 0; k < 4; ++k)
      *(short8*)&Ks[hk][krow][kc0 + k * 8] = kp[k];
    if (tid < 448) {
#pragma unroll
      for (int k = 0; k < 4; ++k)
        *(short8*)&Vs[hv][vrow][vc0 + k * 8] = vp[k];
    } else {
#pragma unroll
      for (int q = 0; q < 8; ++q) {
        const int idx = au * 8 + q;
        Aqs[idx >> 8][(idx & 255) >> 6][idx & 63] = ap[q];
      }
    }
  };

  loadTile(0);
  for (int t = 0; t < 8; ++t) {
    __syncthreads();
    storeTile();
    __syncthreads();
    if (t < 7) loadTile(t + 1);

    // QK from staged K (this wave's half)
    f32x4 accS[4];
#pragma unroll
    for (int ct = 0; ct < 4; ++ct) accS[ct] = (f32x4){0.f, 0.f, 0.f, 0.f};
#pragma unroll
    for (int ct = 0; ct < 4; ++ct) {
#pragma unroll
      for (int ks = 0; ks < 4; ++ks) {
        const short8 bh8 = *(const short8*)&Ks[jh][ct * 16 + fr][ks * 32 + fg * 8];
        accS[ct] = MFMA(aQ[ks], bh8, accS[ct]);
      }
    }

    // distances + folded penalty; P = exp(s)
#pragma unroll
    for (int ct = 0; ct < 4; ++ct) {
      const int jj = ct * 16 + fr;
      const float aj0 = Aqs[jh][0][jj];
      const float aj1 = Aqs[jh][1][jj];
      const float aj2v = Aqs[jh][2][jj];
      const float penF = Aqs[jh][3][jj];
#pragma unroll
      for (int r_ = 0; r_ < 4; ++r_) {
        const float dx = ai0[r_] - aj0;
        const float dy = ai1[r_] - aj1;
        const float dz = ai2[r_] - aj2v;
        const float s = accS[ct][r_]
                      - spw * sqrtf(dx * dx + dy * dy + dz * dz) - penF;
        const float p = __expf(s);
        accS[ct][r_] = p;
        lsum[r_] += p;
      }
    }

    // P tile (wave-private LDS)
#pragma unroll
    for (int ct = 0; ct < 4; ++ct)
#pragma unroll
      for (int r_ = 0; r_ < 4; ++r_)
        P_s[w][fg * 4 + r_][ct * 16 + fr] = f2bf(accS[ct][r_]);

    const short8 aP0 = *(const short8*)&P_s[w][fr][fg * 8];
    const short8 aP1 = *(const short8*)&P_s[w][fr][32 + fg * 8];
#pragma unroll
    for (int ct = 0; ct < 7; ++ct) {
      const short8 b0 = *(const short8*)&Vs[jh][ct * 16 + fr][fg * 8];
      const short8 b1 = *(const short8*)&Vs[jh][ct * 16 + fr][32 + fg * 8];
      f32x4 tacc = MFMA(aP0, b0, accO[ct]);
      accO[ct] = MFMA(aP1, b1, tacc);
    }
  }

  // reduce L across fr lanes
#pragma unroll
  for (int off = 1; off < 16; off <<= 1) {
#pragma unroll
    for (int r_ = 0; r_ < 4; ++r_) lsum[r_] += __shfl_xor(lsum[r_], off);
  }

  __syncthreads();   // all waves done with P_s before Opart overlays it

  // publish partials (bf16 O, fp32 L)
#pragma unroll
  for (int ct = 0; ct < 7; ++ct)
#pragma unroll
    for (int r_ = 0; r_ < 4; ++r_)
      Opart[w][fg * 4 + r_][ct * 16 + fr] = f2bf(accO[ct][r_]);
  if (fr == 0) {
#pragma unroll
    for (int r_ = 0; r_ < 4; ++r_) lst[w][fg * 4 + r_] = lsum[r_];
  }
  __syncthreads();

  if (tid < 64) {
    const int g = tid >> 4, row = tid & 15;
    linv[g][row] = 1.0f / (lst[g][row] + lst[g + 4][row]);
  }
  __syncthreads();

  // epilogue: sum-combine j-halves + rotations + catb writes
  auto comb = [&](int row, int d) -> float {
    const int g = row >> 4, r16 = row & 15;
    return (bf2f(Opart[g][r16][d]) + bf2f(Opart[g + 4][r16][d])) * linv[g][r16];
  };
  for (int u = tid; u < 64 * 103; u += 512) {
    const int lr = u / 103, d = u % 103;
    const int gi = i0 + lr;
    const size_t gl = (size_t)b * NL + gi;
    float val;
    int col;
    if (d < 64) {
      val = comb(lr, d);
      col = h * 64 + d;
    } else if (d < 100) {
      const int v3 = d - 64;
      const int n = v3 % 3;
      const int base = 64 + v3 - n;
      val = comb(lr, base)     * rots[gl * 9 + n]
          + comb(lr, base + 1) * rots[gl * 9 + 3 + n]
          + comb(lr, base + 2) * rots[gl * 9 + 6 + n];
      col = 512 + h * NV3 + v3;
    } else {
      const int n = d - 100;
      const float c0 = comb(lr, 100) - trans[gl * 3 + 0];
      const float c1 = comb(lr, 101) - trans[gl * 3 + 1];
      const float c2 = comb(lr, 102) - trans[gl * 3 + 2];
      val = c0 * rots[gl * 9 + n] + c1 * rots[gl * 9 + 3 + n] + c2 * rots[gl * 9 + 6 + n];
      col = 800 + h * 3 + n;
    }
    catb[gl * KF + col] = f2bf(val);
  }
  if (h == 0) {
    for (int u = tid; u < 64 * 8; u += 512)
      catb[((size_t)b * NL + i0 + (u >> 3)) * KF + 824 + (u & 7)] = 0;
  }
}

} // namespace

extern "C" void kernel_launch(void* const* d_in, const int* in_sizes, int n_in,
                              void* d_out, int out_size, void* d_ws, size_t ws_size,
                              hipStream_t stream)
{
  const float* x       = (const float*)d_in[0];
  const float* mask    = (const float*)d_in[1];
  const float* rots    = (const float*)d_in[2];
  const float* trans   = (const float*)d_in[3];
  const float* w_q     = (const float*)d_in[4];
  const float* w_k     = (const float*)d_in[5];
  const float* w_v     = (const float*)d_in[6];
  const float* w_o     = (const float*)d_in[7];
  const float* w_vq_w  = (const float*)d_in[8];
  const float* w_vq_b  = (const float*)d_in[9];
  const float* w_vk_w  = (const float*)d_in[10];
  const float* w_vk_b  = (const float*)d_in[11];
  const float* w_vv_w  = (const float*)d_in[12];
  const float* w_vv_b  = (const float*)d_in[13];
  const float* w_vo_w  = (const float*)d_in[14];
  const float* w_vo_b  = (const float*)d_in[15];
  const float* w_aq_w  = (const float*)d_in[16];
  const float* w_aq_b  = (const float*)d_in[17];
  const float* w_av_w  = (const float*)d_in[18];
  const float* w_av_b  = (const float*)d_in[19];
  const float* w_ao_w  = (const float*)d_in[20];
  const float* w_ao_b  = (const float*)d_in[21];
  const float* aff_w   = (const float*)d_in[22];
  float* out = (float*)d_out;

  char* base = (char*)d_ws;
  ushort* xh  = (ushort*)base;
  ushort* xl  = xh + (size_t)2048 * 512;
  ushort* wch = xl + (size_t)2048 * 512;
  ushort* qAh = (ushort*)base;                       // 4 MB (over xh+xl)
  float*  aq_t = (float*)(wch + (size_t)2560 * 512); // 196 KB (after wch)
  char* p = base + 9437184;
  ushort* wcat2 = (ushort*)p; p += (size_t)512 * 832 * 2;
  float*  Y     = (float*)p;
  ushort* catb  = (ushort*)Y;
  p += (size_t)2048 * 2560 * 4;
  ushort* kBh = (ushort*)p; p += (size_t)16 * 1024 * 128 * 2;
  ushort* Vt  = (ushort*)p; p += (size_t)16 * 112 * 1024 * 2;
  float* penc = (float*)p;  p += (size_t)2048 * 4;

  k_wprep<<<dim3(40, 13, 3), 256, 0, stream>>>(w_q, w_k, w_v, w_vq_w, w_vk_w,
                                               w_vv_w, w_aq_w, w_av_w,
                                               w_o, w_vo_w, w_ao_w, x,
                                               wch, wcat2, xh, xl);
  k_mm<<<dim3(16, 40), 256, 0, stream>>>(xh, xl, wch, Y, NCAT, 512);
  k_stage<<<dim3(32, 8, 2), 256, 0, stream>>>(Y, rots, trans, mask,
                                              w_vq_b, w_vk_b, w_vv_b,
                                              w_aq_b, w_av_b,
                                              qAh, kBh, Vt, aq_t, penc);
  k_attn<<<256, 512, 0, stream>>>(qAh, kBh, Vt,
                                  aq_t, penc, rots, trans, aff_w, catb);
  k_fin<<<dim3(32, 8), 256, 0, stream>>>(catb, wcat2, w_vo_b, w_ao_b, out);
}

// Round 21
// 101.812 us; speedup vs baseline: 1.1078x; 1.0752x over previous
//
#include <hip/hip_runtime.h>
#include <math.h>

namespace {

typedef __attribute__((ext_vector_type(8))) short short8;
typedef __attribute__((ext_vector_type(4))) float f32x4;

constexpr int NL  = 1024;
constexpr int ND  = 512;
constexpr int NH  = 8;
constexpr int NV3 = 36;
constexpr int NCAT = 2560;   // packed projection output cols (2448 used)
constexpr int KF   = 832;    // final-GEMM K (824 used)

constexpr float SCL_S = 0.044194173824159216f; // 1/sqrt(512)
constexpr float SCL_V = 1.0f / 6.0f;           // 1/sqrt(36)
constexpr float FIXM  = 12.0f;                 // fixed softmax max (logits ~ +-6)

__device__ inline ushort f2bf(float f) {
  uint u = __float_as_uint(f);
  u += 0x7FFFu + ((u >> 16) & 1u);
  return (ushort)(u >> 16);
}
__device__ inline float bf2f(ushort h) { return __uint_as_float((uint)h << 16); }

#define MFMA(a, b, c) __builtin_amdgcn_mfma_f32_16x16x32_bf16((a), (b), (c), 0, 0, 0)

// ---------------------------------------------------------------- k_wprep
__global__ __launch_bounds__(256) void k_wprep(
    const float* __restrict__ wq, const float* __restrict__ wk,
    const float* __restrict__ wv, const float* __restrict__ wvq,
    const float* __restrict__ wvk, const float* __restrict__ wvv,
    const float* __restrict__ waq, const float* __restrict__ wav,
    const float* __restrict__ w_o, const float* __restrict__ w_vo,
    const float* __restrict__ w_ao, const float* __restrict__ x,
    ushort* __restrict__ wch, ushort* __restrict__ wcat2,
    ushort* __restrict__ xh, ushort* __restrict__ xl)
{
  __shared__ float t[64][65];
  const int tid = threadIdx.x;
  const int z = blockIdx.z;
  if (z == 2) {
    const int bid = blockIdx.y * 40 + blockIdx.x;
    if (bid >= 512) return;
    const size_t i = ((size_t)bid * 256 + tid) * 8;
#pragma unroll
    for (int q = 0; q < 2; ++q) {
      const float4 v = *(const float4*)&x[i + q * 4];
      ushort4 h, l;
      h.x = f2bf(v.x); l.x = f2bf(v.x - bf2f(h.x));
      h.y = f2bf(v.y); l.y = f2bf(v.y - bf2f(h.y));
      h.z = f2bf(v.z); l.z = f2bf(v.z - bf2f(h.z));
      h.w = f2bf(v.w); l.w = f2bf(v.w - bf2f(h.w));
      *(ushort4*)&xh[i + q * 4] = h;
      *(ushort4*)&xl[i + q * 4] = l;
    }
    return;
  }
  if (z == 0) { if (blockIdx.y >= 8) return; }
  else        { if (blockIdx.x >= 8) return; }
  const int n0 = blockIdx.x * 64, k0 = blockIdx.y * 64;
  const int rr = tid >> 6, cc = tid & 63;

  for (int p = 0; p < 16; ++p) {
    const int kk = k0 + p * 4 + rr;
    const int nn = n0 + cc;
    float val;
    if (z == 0) {
      if (nn < 1536) {
        const float* w = nn < 512 ? wq : (nn < 1024 ? wk : wv);
        val = w[(size_t)kk * 512 + (nn & 511)];
      } else if (nn < 2400) {
        const float* w = nn < 1824 ? wvq : (nn < 2112 ? wvk : wvv);
        val = w[(size_t)kk * 288 + (nn - 1536) % 288];
      } else if (nn < 2424) val = waq[(size_t)kk * 24 + nn - 2400];
      else if (nn < 2448)   val = wav[(size_t)kk * 24 + nn - 2424];
      else val = 0.f;
    } else {
      if (kk < 512)      val = w_o [(size_t)kk * 512 + nn];
      else if (kk < 800) val = w_vo[(size_t)(kk - 512) * 512 + nn];
      else if (kk < 824) val = w_ao[(size_t)(kk - 800) * 512 + nn];
      else val = 0.f;
    }
    t[p * 4 + rr][cc] = val;
  }
  __syncthreads();
  for (int p = 0; p < 16; ++p) {
    const int nn = p * 4 + rr;
    const int kk = cc;
    const float val = t[kk][nn];
    if (z == 0) wch[(size_t)(n0 + nn) * 512 + k0 + kk] = f2bf(val);
    else        wcat2[(size_t)(n0 + nn) * 832 + k0 + kk] = f2bf(val);
  }
}

// ---------------------------------------------------------------- k_mm
__global__ __launch_bounds__(256) void k_mm(
    const ushort* __restrict__ Ah, const ushort* __restrict__ Al,
    const ushort* __restrict__ Bh,
    float* __restrict__ Y, int N, int K)
{
  __shared__ __align__(16) ushort Ahs[128][40];
  __shared__ __align__(16) ushort Als[128][40];
  __shared__ __align__(16) ushort Bhs[64][40];
  const int tid = threadIdx.x;
  const int m0 = blockIdx.x * 128, n0 = blockIdx.y * 64;
  const int w = tid >> 6, lane = tid & 63;
  const int wm = (w & 1) * 64, wn = (w >> 1) * 32;
  const int fr = lane & 15, fg = lane >> 4;

  f32x4 acc[4][2];
#pragma unroll
  for (int i = 0; i < 4; ++i)
#pragma unroll
    for (int j = 0; j < 2; ++j) acc[i][j] = (f32x4){0.f, 0.f, 0.f, 0.f};

  const int ar = tid >> 1, ak = (tid & 1) * 16;
  const int br = tid >> 2, bk = (tid & 3) * 8;
  const ushort* agh = Ah + (size_t)(m0 + ar) * K + ak;
  const ushort* agl = Al + (size_t)(m0 + ar) * K + ak;
  const ushort* bgh = Bh + (size_t)(n0 + br) * K + bk;
  short8 pah0 = *(const short8*)agh, pah1 = *(const short8*)(agh + 8);
  short8 pal0 = *(const short8*)agl, pal1 = *(const short8*)(agl + 8);
  short8 pbh0 = *(const short8*)bgh;

  const int NT = K >> 5;
  for (int kt = 0; kt < NT; ++kt) {
    __syncthreads();
    *(short8*)&Ahs[ar][ak] = pah0; *(short8*)&Ahs[ar][ak + 8] = pah1;
    *(short8*)&Als[ar][ak] = pal0; *(short8*)&Als[ar][ak + 8] = pal1;
    *(short8*)&Bhs[br][bk] = pbh0;
    __syncthreads();
    if (kt + 1 < NT) {
      const size_t off = (size_t)(kt + 1) * 32;
      pah0 = *(const short8*)(agh + off); pah1 = *(const short8*)(agh + off + 8);
      pal0 = *(const short8*)(agl + off); pal1 = *(const short8*)(agl + off + 8);
      pbh0 = *(const short8*)(bgh + off);
    }
    short8 fah[4], fal[4], fbh[2];
#pragma unroll
    for (int i = 0; i < 4; ++i) {
      fah[i] = *(const short8*)&Ahs[wm + i * 16 + fr][fg * 8];
      fal[i] = *(const short8*)&Als[wm + i * 16 + fr][fg * 8];
    }
#pragma unroll
    for (int j = 0; j < 2; ++j)
      fbh[j] = *(const short8*)&Bhs[wn + j * 16 + fr][fg * 8];
#pragma unroll
    for (int i = 0; i < 4; ++i)
#pragma unroll
      for (int j = 0; j < 2; ++j) {
        f32x4 t = MFMA(fah[i], fbh[j], acc[i][j]);
        acc[i][j] = MFMA(fal[i], fbh[j], t);
      }
  }

  const int rb = fg * 4;
#pragma unroll
  for (int i = 0; i < 4; ++i)
#pragma unroll
    for (int j = 0; j < 2; ++j) {
      const int n = n0 + wn + j * 16 + fr;
#pragma unroll
      for (int r = 0; r < 4; ++r) {
        const int m = m0 + wm + i * 16 + rb + r;
        Y[(size_t)m * N + n] = acc[i][j][r];
      }
    }
}

// ---------------------------------------------------------------- k_fin
__global__ __launch_bounds__(256) void k_fin(
    const ushort* __restrict__ A, const ushort* __restrict__ Bt,
    const float* __restrict__ b_vo, const float* __restrict__ b_ao,
    float* __restrict__ out)
{
  __shared__ __align__(16) ushort As[64][40];
  __shared__ __align__(16) ushort Bs[64][40];
  const int tid = threadIdx.x;
  const int m0 = blockIdx.x * 64, n0 = blockIdx.y * 64;
  const int w = tid >> 6, lane = tid & 63;
  const int wm = (w & 1) * 32, wn = (w >> 1) * 32;
  const int fr = lane & 15, fg = lane >> 4;
  const int K = KF;

  f32x4 acc[2][2];
#pragma unroll
  for (int i = 0; i < 2; ++i)
#pragma unroll
    for (int j = 0; j < 2; ++j) acc[i][j] = (f32x4){0.f, 0.f, 0.f, 0.f};

  const int ar = tid >> 2, ak = (tid & 3) * 8;
  const ushort* ag = A + (size_t)(m0 + ar) * K + ak;
  const ushort* bg = Bt + (size_t)(n0 + ar) * K + ak;
  short8 a0 = *(const short8*)ag;
  short8 b0 = *(const short8*)bg;

  const int NT = K >> 5;
  for (int kt = 0; kt < NT; ++kt) {
    __syncthreads();
    *(short8*)&As[ar][ak] = a0;
    *(short8*)&Bs[ar][ak] = b0;
    __syncthreads();
    if (kt + 1 < NT) {
      const size_t off = (size_t)(kt + 1) * 32;
      a0 = *(const short8*)(ag + off);
      b0 = *(const short8*)(bg + off);
    }
    short8 aF[2], bF[2];
#pragma unroll
    for (int i = 0; i < 2; ++i) aF[i] = *(const short8*)&As[wm + i * 16 + fr][fg * 8];
#pragma unroll
    for (int j = 0; j < 2; ++j) bF[j] = *(const short8*)&Bs[wn + j * 16 + fr][fg * 8];
#pragma unroll
    for (int i = 0; i < 2; ++i)
#pragma unroll
      for (int j = 0; j < 2; ++j)
        acc[i][j] = MFMA(aF[i], bF[j], acc[i][j]);
  }

  const int rb = fg * 4;
#pragma unroll
  for (int j = 0; j < 2; ++j) {
    const int n = n0 + wn + j * 16 + fr;
    const float bias = b_vo[n] + b_ao[n];
#pragma unroll
    for (int i = 0; i < 2; ++i)
#pragma unroll
      for (int r = 0; r < 4; ++r) {
        const int m = m0 + wm + i * 16 + rb + r;
        out[(size_t)m * ND + n] = acc[i][j][r] + bias;
      }
  }
}

// ---------------------------------------------------------------- k_stage
__global__ __launch_bounds__(256) void k_stage(
    const float* __restrict__ Y,
    const float* __restrict__ rots, const float* __restrict__ trans,
    const float* __restrict__ mask,
    const float* __restrict__ bvq, const float* __restrict__ bvk,
    const float* __restrict__ bvv, const float* __restrict__ baq,
    const float* __restrict__ bav,
    ushort* __restrict__ qAh, ushort* __restrict__ kBh,
    ushort* __restrict__ Vt,
    float* __restrict__ aq_t, float* __restrict__ penc)
{
  __shared__ __align__(16) char sbuf[36864];
  const int tid = threadIdx.x;

  if (blockIdx.z == 0) {
    float (*t0)[65] = (float(*)[65])sbuf;
    float (*t1)[72] = (float(*)[72])(sbuf + 16640);
    const int l0 = blockIdx.x * 64, h = blockIdx.y;
    const int b = l0 >> 10, ll0 = l0 & 1023;
    const int bh = b * NH + h;
    const int rr = tid >> 6, cc = tid & 63;
    const float inv = powf(10000.f, -(float)(cc & ~1) / 64.f);
    const bool odd = (cc & 1) != 0;

    for (int p = 0; p < 16; ++p) {
      const int r = p * 4 + rr;
      t0[r][cc] = Y[(size_t)(l0 + r) * NCAT + h * 64 + cc];
    }
    __syncthreads();
    for (int p = 0; p < 16; ++p) {
      const int r = p * 4 + rr;
      float sv, cv;
      __sincosf((float)(ll0 + r) * inv, &sv, &cv);
      const float e = t0[r][cc & ~1], o = t0[r][(cc & ~1) + 1];
      const float val = (odd ? fmaf(e, sv, o * cv) : fmaf(e, cv, -o * sv)) * SCL_S;
      qAh[((size_t)bh * NL + ll0 + r) * 128 + cc] = f2bf(val);
    }
    __syncthreads();
    for (int p = 0; p < 16; ++p) {
      const int r = p * 4 + rr;
      t0[r][cc] = Y[(size_t)(l0 + r) * NCAT + 512 + h * 64 + cc];
    }
    __syncthreads();
    for (int p = 0; p < 16; ++p) {
      const int r = p * 4 + rr;
      float sv, cv;
      __sincosf((float)(ll0 + r) * inv, &sv, &cv);
      const float e = t0[r][cc & ~1], o = t0[r][(cc & ~1) + 1];
      const float val = odd ? fmaf(e, sv, o * cv) : fmaf(e, cv, -o * sv);
      kBh[((size_t)bh * NL + ll0 + r) * 128 + cc] = f2bf(val);
    }
    for (int p = 0; p < 16; ++p) {
      const int r = p * 4 + rr;
      t1[cc][r] = Y[(size_t)(l0 + r) * NCAT + 1024 + h * 64 + cc];
    }
    __syncthreads();
    for (int p = 0; p < 16; ++p) {
      const int hd = p * 4 + rr;
      Vt[((size_t)bh * 112 + hd) * NL + ll0 + cc] = f2bf(t1[hd][cc]);
    }
    for (int u = tid; u < 9 * 64; u += 256)
      Vt[((size_t)bh * 112 + 103 + (u >> 6)) * NL + ll0 + (u & 63)] = 0;
    return;
  }

  float (*ys)[912] = (float(*)[912])sbuf;
  const int bid = blockIdx.y * 32 + blockIdx.x;
  const int tb = bid * 8;
  const int b = tb >> 10;

  for (int t = 0; t < 8; ++t)
    for (int n = tid; n < 912; n += 256)
      ys[t][n] = Y[(size_t)(tb + t) * NCAT + 1536 + n];
  __syncthreads();

  for (int u = tid; u < 8 * 288; u += 256) {
    const int t = u / 288, n = u % 288;
    const int l = tb + t, ll = l & (NL - 1);
    const int c = n % 3, base = n - c;
    const int h = n / NV3, m = n % NV3;
    const float r0 = rots[(size_t)l * 9 + c * 3 + 0];
    const float r1 = rots[(size_t)l * 9 + c * 3 + 1];
    const float r2 = rots[(size_t)l * 9 + c * 3 + 2];
    const float vqv = (r0 * (ys[t][base] + bvq[base])
                     + r1 * (ys[t][base + 1] + bvq[base + 1])
                     + r2 * (ys[t][base + 2] + bvq[base + 2])) * SCL_V;
    const float vkv = r0 * (ys[t][288 + base] + bvk[base])
                    + r1 * (ys[t][289 + base] + bvk[base + 1])
                    + r2 * (ys[t][290 + base] + bvk[base + 2]);
    const float vvv = r0 * (ys[t][576 + base] + bvv[base])
                    + r1 * (ys[t][577 + base] + bvv[base + 1])
                    + r2 * (ys[t][578 + base] + bvv[base + 2]);
    const size_t row = ((size_t)(b * NH + h) * NL + ll) * 128 + 64 + m;
    qAh[row] = f2bf(vqv);
    kBh[row] = f2bf(vkv);
    Vt[((size_t)(b * NH + h) * 112 + 64 + m) * NL + ll] = f2bf(vvv);
  }
  for (int u = tid; u < 8 * 8 * 14; u += 256) {
    const int t = u / 112, rem = u % 112, h = rem / 14, k = rem % 14;
    const int ll = (tb + t) & (NL - 1);
    const size_t row = ((size_t)(b * NH + h) * NL + ll) * 128 + 100 + 2 * k;
    *(uint*)&qAh[row] = 0;
  }
  for (int u = tid; u < 64; u += 256) {
    const int t = u >> 3, h = u & 7;
    const int l = tb + t, ll = l & (NL - 1);
    const int base = h * 3;
    const size_t tok = (size_t)(b * NH + h) * NL + ll;
#pragma unroll
    for (int c = 0; c < 3; ++c) {
      const float aqv =
          rots[(size_t)l * 9 + c * 3 + 0] * (ys[t][864 + base] + baq[base])
        + rots[(size_t)l * 9 + c * 3 + 1] * (ys[t][865 + base] + baq[base + 1])
        + rots[(size_t)l * 9 + c * 3 + 2] * (ys[t][866 + base] + baq[base + 2])
        + trans[(size_t)l * 3 + c];
      aq_t[((size_t)(b * NH + h) * 3 + c) * NL + ll] = aqv;
    }
#pragma unroll
    for (int k = 0; k < 14; ++k)
      *(uint*)&kBh[tok * 128 + 100 + 2 * k] = 0;
  }
  for (int u = tid; u < 8 * 24; u += 256) {
    const int t = u / 24, n = u % 24;
    const int l = tb + t, ll = l & (NL - 1);
    const int c = n % 3, h = n / 3, base = h * 3;
    const float val = rots[(size_t)l * 9 + c * 3 + 0] * (ys[t][888 + base] + bav[base])
                    + rots[(size_t)l * 9 + c * 3 + 1] * (ys[t][889 + base] + bav[base + 1])
                    + rots[(size_t)l * 9 + c * 3 + 2] * (ys[t][890 + base] + bav[base + 2])
                    + trans[(size_t)l * 3 + c];
    Vt[((size_t)(b * NH + h) * 112 + 100 + c) * NL + ll] = f2bf(val);
  }
  for (int u = tid; u < 8; u += 256) {
    const int ll = (tb + u) & (NL - 1);
    penc[(size_t)b * NL + ll] = 1e6f * (1.0f - mask[(size_t)b * NL + ll]);
  }
}

// ---------------------------------------------------------------- k_attn
// 8-wave cooperative flash attention: 512 thr = 4 row-groups x 2 j-halves.
// Each iteration stages BOTH halves' 64-wide K/V/aq tiles; wave (rg,jh)
// computes its half. Fixed-max softmax -> cross-wave combine is plain sum.
// Grid 256 = 16 bh x 16 row-tiles (64 rows), XCD-swizzled; 8 waves/CU.
__global__ __launch_bounds__(512) void k_attn(
    const ushort* __restrict__ qAh,
    const ushort* __restrict__ kBh, const ushort* __restrict__ Vt,
    const float* __restrict__ aq_t, const float* __restrict__ penc,
    const float* __restrict__ rots, const float* __restrict__ trans,
    const float* __restrict__ affw,
    ushort* __restrict__ catb)
{
  __shared__ __align__(16) ushort Ks[2][64][136];
  __shared__ __align__(16) ushort Vs[2][112][72];
  __shared__ float Aqs[2][4][64];
  __shared__ __align__(16) char uni[28672];   // P_s (loop) / Opart (epilogue)
  __shared__ float lst[8][16];
  __shared__ float linv[4][16];

  ushort (*P_s)[16][72]   = (ushort(*)[16][72])uni;
  ushort (*Opart)[16][112] = (ushort(*)[16][112])uni;

  const int blk = blockIdx.x;
  const int bh  = (blk & 7) * 2 + (blk >> 7);
  const int i0  = ((blk >> 3) & 15) * 64;
  const int b = bh >> 3, h = bh & 7;
  const int tid = threadIdx.x;
  const int w = tid >> 6, lane = tid & 63;
  const int rg = w & 3, jh = w >> 2;
  const int fr = lane & 15, fg = lane >> 4;
  const int irow = i0 + rg * 16;

  const float spw = logf(1.0f + expf(affw[h]));

  short8 aQ[4];
  const size_t qrow = ((size_t)bh * NL + irow + fr) * 128;
#pragma unroll
  for (int ks = 0; ks < 4; ++ks)
    aQ[ks] = *(const short8*)&qAh[qrow + ks * 32 + fg * 8];

  const float* aqx = aq_t + (size_t)bh * 3 * NL;
  float ai0[4], ai1[4], ai2[4];
#pragma unroll
  for (int r_ = 0; r_ < 4; ++r_) {
    const int row = irow + fg * 4 + r_;
    ai0[r_] = aqx[row];
    ai1[r_] = aqx[NL + row];
    ai2[r_] = aqx[2 * NL + row];
  }

  float lsum[4] = {0.f, 0.f, 0.f, 0.f};
  f32x4 accO[7];
#pragma unroll
  for (int ct = 0; ct < 7; ++ct) accO[ct] = (f32x4){0.f, 0.f, 0.f, 0.f};

  // staging roles (512 threads stage 2 half-tiles per iteration)
  const int hk = tid >> 8, krow = (tid >> 2) & 63, kc0 = (tid & 3) * 32;
  const int hv = (tid < 448) ? tid / 224 : 0;
  const int vrem = (tid < 448) ? tid % 224 : 0;
  const int vrow = vrem >> 1, vc0 = (vrem & 1) * 32;
  const int au = tid - 448;                      // tid>=448: aq/pen (64 thr)
  const size_t kgb = (size_t)bh * NL * 128 + (size_t)(hk * 512 + krow) * 128 + kc0;
  const size_t vgb = ((size_t)bh * 112 + vrow) * NL + hv * 512 + vc0;

  short8 kp[4], vp[4];
  float ap[8];

  auto loadTile = [&](int t) {
#pragma unroll
    for (int k = 0; k < 4; ++k)
      kp[k] = *(const short8*)&kBh[kgb + (size_t)t * 64 * 128 + k * 8];
    if (tid < 448) {
#pragma unroll
      for (int k = 0; k < 4; ++k)
        vp[k] = *(const short8*)&Vt[vgb + t * 64 + k * 8];
    } else {
#pragma unroll
      for (int q = 0; q < 8; ++q) {
        const int idx = au * 8 + q;              // 0..511
        const int ha = idx >> 8, rem2 = idx & 255;
        const int c = rem2 >> 6, jj = rem2 & 63;
        const int j = ha * 512 + t * 64 + jj;
        ap[q] = (c < 3) ? aqx[c * NL + j]
                        : penc[(size_t)b * NL + j];
      }
    }
  };
  auto storeTile = [&]() {
#pragma unroll
    for (int k = 0; k < 4; ++k)
      *(short8*)&Ks[hk][krow][kc0 + k * 8] = kp[k];
    if (tid < 448) {
#pragma unroll
      for (int k = 0; k < 4; ++k)
        *(short8*)&Vs[hv][vrow][vc0 + k * 8] = vp[k];
    } else {
#pragma unroll
      for (int q = 0; q < 8; ++q) {
        const int idx = au * 8 + q;
        Aqs[idx >> 8][(idx & 255) >> 6][idx & 63] = ap[q];
      }
    }
  };

  loadTile(0);
  for (int t = 0; t < 8; ++t) {
    __syncthreads();
    storeTile();
    __syncthreads();
    if (t < 7) loadTile(t + 1);

    // QK from staged K (this wave's half)
    f32x4 accS[4];
#pragma unroll
    for (int ct = 0; ct < 4; ++ct) accS[ct] = (f32x4){0.f, 0.f, 0.f, 0.f};
#pragma unroll
    for (int ct = 0; ct < 4; ++ct) {
#pragma unroll
      for (int ks = 0; ks < 4; ++ks) {
        const short8 bh8 = *(const short8*)&Ks[jh][ct * 16 + fr][ks * 32 + fg * 8];
        accS[ct] = MFMA(aQ[ks], bh8, accS[ct]);
      }
    }

    // distances + penalty; P = exp(s - FIXM)
#pragma unroll
    for (int ct = 0; ct < 4; ++ct) {
      const int jj = ct * 16 + fr;
      const float aj0 = Aqs[jh][0][jj];
      const float aj1 = Aqs[jh][1][jj];
      const float aj2v = Aqs[jh][2][jj];
      const float pen = Aqs[jh][3][jj];
#pragma unroll
      for (int r_ = 0; r_ < 4; ++r_) {
        const float dx = ai0[r_] - aj0;
        const float dy = ai1[r_] - aj1;
        const float dz = ai2[r_] - aj2v;
        const float s = accS[ct][r_]
                      - spw * sqrtf(dx * dx + dy * dy + dz * dz) - pen;
        const float p = __expf(s - FIXM);
        accS[ct][r_] = p;
        lsum[r_] += p;
      }
    }

    // P tile (wave-private LDS)
#pragma unroll
    for (int ct = 0; ct < 4; ++ct)
#pragma unroll
      for (int r_ = 0; r_ < 4; ++r_)
        P_s[w][fg * 4 + r_][ct * 16 + fr] = f2bf(accS[ct][r_]);

    const short8 aP0 = *(const short8*)&P_s[w][fr][fg * 8];
    const short8 aP1 = *(const short8*)&P_s[w][fr][32 + fg * 8];
#pragma unroll
    for (int ct = 0; ct < 7; ++ct) {
      const short8 b0 = *(const short8*)&Vs[jh][ct * 16 + fr][fg * 8];
      const short8 b1 = *(const short8*)&Vs[jh][ct * 16 + fr][32 + fg * 8];
      f32x4 tacc = MFMA(aP0, b0, accO[ct]);
      accO[ct] = MFMA(aP1, b1, tacc);
    }
  }

  // reduce L across fr lanes
#pragma unroll
  for (int off = 1; off < 16; off <<= 1) {
#pragma unroll
    for (int r_ = 0; r_ < 4; ++r_) lsum[r_] += __shfl_xor(lsum[r_], off);
  }

  __syncthreads();   // all waves done with P_s before Opart overlays it

  // publish partials (bf16 O, fp32 L)
#pragma unroll
  for (int ct = 0; ct < 7; ++ct)
#pragma unroll
    for (int r_ = 0; r_ < 4; ++r_)
      Opart[w][fg * 4 + r_][ct * 16 + fr] = f2bf(accO[ct][r_]);
  if (fr == 0) {
#pragma unroll
    for (int r_ = 0; r_ < 4; ++r_) lst[w][fg * 4 + r_] = lsum[r_];
  }
  __syncthreads();

  if (tid < 64) {
    const int g = tid >> 4, row = tid & 15;
    linv[g][row] = 1.0f / (lst[g][row] + lst[g + 4][row]);
  }
  __syncthreads();

  // epilogue: sum-combine j-halves + rotations + catb writes
  auto comb = [&](int row, int d) -> float {
    const int g = row >> 4, r16 = row & 15;
    return (bf2f(Opart[g][r16][d]) + bf2f(Opart[g + 4][r16][d])) * linv[g][r16];
  };
  for (int u = tid; u < 64 * 103; u += 512) {
    const int lr = u / 103, d = u % 103;
    const int gi = i0 + lr;
    const size_t gl = (size_t)b * NL + gi;
    float val;
    int col;
    if (d < 64) {
      val = comb(lr, d);
      col = h * 64 + d;
    } else if (d < 100) {
      const int v3 = d - 64;
      const int n = v3 % 3;
      const int base = 64 + v3 - n;
      val = comb(lr, base)     * rots[gl * 9 + n]
          + comb(lr, base + 1) * rots[gl * 9 + 3 + n]
          + comb(lr, base + 2) * rots[gl * 9 + 6 + n];
      col = 512 + h * NV3 + v3;
    } else {
      const int n = d - 100;
      const float c0 = comb(lr, 100) - trans[gl * 3 + 0];
      const float c1 = comb(lr, 101) - trans[gl * 3 + 1];
      const float c2 = comb(lr, 102) - trans[gl * 3 + 2];
      val = c0 * rots[gl * 9 + n] + c1 * rots[gl * 9 + 3 + n] + c2 * rots[gl * 9 + 6 + n];
      col = 800 + h * 3 + n;
    }
    catb[gl * KF + col] = f2bf(val);
  }
  if (h == 0) {
    for (int u = tid; u < 64 * 8; u += 512)
      catb[((size_t)b * NL + i0 + (u >> 3)) * KF + 824 + (u & 7)] = 0;
  }
}

} // namespace

extern "C" void kernel_launch(void* const* d_in, const int* in_sizes, int n_in,
                              void* d_out, int out_size, void* d_ws, size_t ws_size,
                              hipStream_t stream)
{
  const float* x       = (const float*)d_in[0];
  const float* mask    = (const float*)d_in[1];
  const float* rots    = (const float*)d_in[2];
  const float* trans   = (const float*)d_in[3];
  const float* w_q     = (const float*)d_in[4];
  const float* w_k     = (const float*)d_in[5];
  const float* w_v     = (const float*)d_in[6];
  const float* w_o     = (const float*)d_in[7];
  const float* w_vq_w  = (const float*)d_in[8];
  const float* w_vq_b  = (const float*)d_in[9];
  const float* w_vk_w  = (const float*)d_in[10];
  const float* w_vk_b  = (const float*)d_in[11];
  const float* w_vv_w  = (const float*)d_in[12];
  const float* w_vv_b  = (const float*)d_in[13];
  const float* w_vo_w  = (const float*)d_in[14];
  const float* w_vo_b  = (const float*)d_in[15];
  const float* w_aq_w  = (const float*)d_in[16];
  const float* w_aq_b  = (const float*)d_in[17];
  const float* w_av_w  = (const float*)d_in[18];
  const float* w_av_b  = (const float*)d_in[19];
  const float* w_ao_w  = (const float*)d_in[20];
  const float* w_ao_b  = (const float*)d_in[21];
  const float* aff_w   = (const float*)d_in[22];
  float* out = (float*)d_out;

  char* base = (char*)d_ws;
  ushort* xh  = (ushort*)base;
  ushort* xl  = xh + (size_t)2048 * 512;
  ushort* wch = xl + (size_t)2048 * 512;
  ushort* qAh = (ushort*)base;                       // 4 MB (over xh+xl)
  float*  aq_t = (float*)(wch + (size_t)2560 * 512); // 196 KB (after wch)
  char* p = base + 9437184;
  ushort* wcat2 = (ushort*)p; p += (size_t)512 * 832 * 2;
  float*  Y     = (float*)p;
  ushort* catb  = (ushort*)Y;
  p += (size_t)2048 * 2560 * 4;
  ushort* kBh = (ushort*)p; p += (size_t)16 * 1024 * 128 * 2;
  ushort* Vt  = (ushort*)p; p += (size_t)16 * 112 * 1024 * 2;
  float* penc = (float*)p;  p += (size_t)2048 * 4;

  k_wprep<<<dim3(40, 13, 3), 256, 0, stream>>>(w_q, w_k, w_v, w_vq_w, w_vk_w,
                                               w_vv_w, w_aq_w, w_av_w,
                                               w_o, w_vo_w, w_ao_w, x,
                                               wch, wcat2, xh, xl);
  k_mm<<<dim3(16, 40), 256, 0, stream>>>(xh, xl, wch, Y, NCAT, 512);
  k_stage<<<dim3(32, 8, 2), 256, 0, stream>>>(Y, rots, trans, mask,
                                              w_vq_b, w_vk_b, w_vv_b,
                                              w_aq_b, w_av_b,
                                              qAh, kBh, Vt, aq_t, penc);
  k_attn<<<256, 512, 0, stream>>>(qAh, kBh, Vt,
                                  aq_t, penc, rots, trans, aff_w, catb);
  k_fin<<<dim3(32, 8), 256, 0, stream>>>(catb, wcat2, w_vo_b, w_ao_b, out);
}

// Round 22
// 101.177 us; speedup vs baseline: 1.1148x; 1.0063x over previous
//
#include <hip/hip_runtime.h>
#include <math.h>

namespace {

typedef __attribute__((ext_vector_type(8))) short short8;
typedef __attribute__((ext_vector_type(4))) float f32x4;

constexpr int NL  = 1024;
constexpr int ND  = 512;
constexpr int NH  = 8;
constexpr int NV3 = 36;
constexpr int NCAT = 2560;   // packed projection output cols (2448 used)
constexpr int KF   = 832;    // final-GEMM K (824 used)

constexpr float SCL_S = 0.044194173824159216f; // 1/sqrt(512)
constexpr float SCL_V = 1.0f / 6.0f;           // 1/sqrt(36)
constexpr float FIXM  = 12.0f;                 // fixed softmax max (logits ~ +-6)

__device__ inline ushort f2bf(float f) {
  uint u = __float_as_uint(f);
  u += 0x7FFFu + ((u >> 16) & 1u);
  return (ushort)(u >> 16);
}
__device__ inline float bf2f(ushort h) { return __uint_as_float((uint)h << 16); }

#define MFMA(a, b, c) __builtin_amdgcn_mfma_f32_16x16x32_bf16((a), (b), (c), 0, 0, 0)

// ---------------------------------------------------------------- k_wprep
__global__ __launch_bounds__(256) void k_wprep(
    const float* __restrict__ wq, const float* __restrict__ wk,
    const float* __restrict__ wv, const float* __restrict__ wvq,
    const float* __restrict__ wvk, const float* __restrict__ wvv,
    const float* __restrict__ waq, const float* __restrict__ wav,
    const float* __restrict__ w_o, const float* __restrict__ w_vo,
    const float* __restrict__ w_ao, const float* __restrict__ x,
    ushort* __restrict__ wch, ushort* __restrict__ wcat2,
    ushort* __restrict__ xh, ushort* __restrict__ xl)
{
  __shared__ float t[64][65];
  const int tid = threadIdx.x;
  const int z = blockIdx.z;
  if (z == 2) {
    const int bid = blockIdx.y * 40 + blockIdx.x;
    if (bid >= 512) return;
    const size_t i = ((size_t)bid * 256 + tid) * 8;
#pragma unroll
    for (int q = 0; q < 2; ++q) {
      const float4 v = *(const float4*)&x[i + q * 4];
      ushort4 h, l;
      h.x = f2bf(v.x); l.x = f2bf(v.x - bf2f(h.x));
      h.y = f2bf(v.y); l.y = f2bf(v.y - bf2f(h.y));
      h.z = f2bf(v.z); l.z = f2bf(v.z - bf2f(h.z));
      h.w = f2bf(v.w); l.w = f2bf(v.w - bf2f(h.w));
      *(ushort4*)&xh[i + q * 4] = h;
      *(ushort4*)&xl[i + q * 4] = l;
    }
    return;
  }
  if (z == 0) { if (blockIdx.y >= 8) return; }
  else        { if (blockIdx.x >= 8) return; }
  const int n0 = blockIdx.x * 64, k0 = blockIdx.y * 64;
  const int rr = tid >> 6, cc = tid & 63;

  for (int p = 0; p < 16; ++p) {
    const int kk = k0 + p * 4 + rr;
    const int nn = n0 + cc;
    float val;
    if (z == 0) {
      if (nn < 1536) {
        const float* w = nn < 512 ? wq : (nn < 1024 ? wk : wv);
        val = w[(size_t)kk * 512 + (nn & 511)];
      } else if (nn < 2400) {
        const float* w = nn < 1824 ? wvq : (nn < 2112 ? wvk : wvv);
        val = w[(size_t)kk * 288 + (nn - 1536) % 288];
      } else if (nn < 2424) val = waq[(size_t)kk * 24 + nn - 2400];
      else if (nn < 2448)   val = wav[(size_t)kk * 24 + nn - 2424];
      else val = 0.f;
    } else {
      if (kk < 512)      val = w_o [(size_t)kk * 512 + nn];
      else if (kk < 800) val = w_vo[(size_t)(kk - 512) * 512 + nn];
      else if (kk < 824) val = w_ao[(size_t)(kk - 800) * 512 + nn];
      else val = 0.f;
    }
    t[p * 4 + rr][cc] = val;
  }
  __syncthreads();
  for (int p = 0; p < 16; ++p) {
    const int nn = p * 4 + rr;
    const int kk = cc;
    const float val = t[kk][nn];
    if (z == 0) wch[(size_t)(n0 + nn) * 512 + k0 + kk] = f2bf(val);
    else        wcat2[(size_t)(n0 + nn) * 832 + k0 + kk] = f2bf(val);
  }
}

// ---------------------------------------------------------------- k_mm
// 1-barrier double-buffered LDS: barrier -> issue next loads ->
// compute buf[kt&1] -> store buf[(kt+1)&1]. Math identical to 2-barrier.
__global__ __launch_bounds__(256) void k_mm(
    const ushort* __restrict__ Ah, const ushort* __restrict__ Al,
    const ushort* __restrict__ Bh,
    float* __restrict__ Y, int N, int K)
{
  __shared__ __align__(16) ushort Ahs[2][128][40];
  __shared__ __align__(16) ushort Als[2][128][40];
  __shared__ __align__(16) ushort Bhs[2][64][40];
  const int tid = threadIdx.x;
  const int m0 = blockIdx.x * 128, n0 = blockIdx.y * 64;
  const int w = tid >> 6, lane = tid & 63;
  const int wm = (w & 1) * 64, wn = (w >> 1) * 32;
  const int fr = lane & 15, fg = lane >> 4;

  f32x4 acc[4][2];
#pragma unroll
  for (int i = 0; i < 4; ++i)
#pragma unroll
    for (int j = 0; j < 2; ++j) acc[i][j] = (f32x4){0.f, 0.f, 0.f, 0.f};

  const int ar = tid >> 1, ak = (tid & 1) * 16;
  const int br = tid >> 2, bk = (tid & 3) * 8;
  const ushort* agh = Ah + (size_t)(m0 + ar) * K + ak;
  const ushort* agl = Al + (size_t)(m0 + ar) * K + ak;
  const ushort* bgh = Bh + (size_t)(n0 + br) * K + bk;
  short8 pah0 = *(const short8*)agh, pah1 = *(const short8*)(agh + 8);
  short8 pal0 = *(const short8*)agl, pal1 = *(const short8*)(agl + 8);
  short8 pbh0 = *(const short8*)bgh;

  // prologue: stage tile 0 into buffer 0 (no barrier needed yet)
  *(short8*)&Ahs[0][ar][ak] = pah0; *(short8*)&Ahs[0][ar][ak + 8] = pah1;
  *(short8*)&Als[0][ar][ak] = pal0; *(short8*)&Als[0][ar][ak + 8] = pal1;
  *(short8*)&Bhs[0][br][bk] = pbh0;

  const int NT = K >> 5;
  for (int kt = 0; kt < NT; ++kt) {
    __syncthreads();   // buf[kt&1] stores visible; prior reads of buf[(kt+1)&1] done
    const int cur = kt & 1, nxt = (kt + 1) & 1;
    if (kt + 1 < NT) {
      const size_t off = (size_t)(kt + 1) * 32;
      pah0 = *(const short8*)(agh + off); pah1 = *(const short8*)(agh + off + 8);
      pal0 = *(const short8*)(agl + off); pal1 = *(const short8*)(agl + off + 8);
      pbh0 = *(const short8*)(bgh + off);
    }
    short8 fah[4], fal[4], fbh[2];
#pragma unroll
    for (int i = 0; i < 4; ++i) {
      fah[i] = *(const short8*)&Ahs[cur][wm + i * 16 + fr][fg * 8];
      fal[i] = *(const short8*)&Als[cur][wm + i * 16 + fr][fg * 8];
    }
#pragma unroll
    for (int j = 0; j < 2; ++j)
      fbh[j] = *(const short8*)&Bhs[cur][wn + j * 16 + fr][fg * 8];
#pragma unroll
    for (int i = 0; i < 4; ++i)
#pragma unroll
      for (int j = 0; j < 2; ++j) {
        f32x4 t = MFMA(fah[i], fbh[j], acc[i][j]);
        acc[i][j] = MFMA(fal[i], fbh[j], t);
      }
    if (kt + 1 < NT) {
      *(short8*)&Ahs[nxt][ar][ak] = pah0; *(short8*)&Ahs[nxt][ar][ak + 8] = pah1;
      *(short8*)&Als[nxt][ar][ak] = pal0; *(short8*)&Als[nxt][ar][ak + 8] = pal1;
      *(short8*)&Bhs[nxt][br][bk] = pbh0;
    }
  }

  const int rb = fg * 4;
#pragma unroll
  for (int i = 0; i < 4; ++i)
#pragma unroll
    for (int j = 0; j < 2; ++j) {
      const int n = n0 + wn + j * 16 + fr;
#pragma unroll
      for (int r = 0; r < 4; ++r) {
        const int m = m0 + wm + i * 16 + rb + r;
        Y[(size_t)m * N + n] = acc[i][j][r];
      }
    }
}

// ---------------------------------------------------------------- k_fin
// 1-barrier double-buffered LDS (same pattern as k_mm).
__global__ __launch_bounds__(256) void k_fin(
    const ushort* __restrict__ A, const ushort* __restrict__ Bt,
    const float* __restrict__ b_vo, const float* __restrict__ b_ao,
    float* __restrict__ out)
{
  __shared__ __align__(16) ushort As[2][64][40];
  __shared__ __align__(16) ushort Bs[2][64][40];
  const int tid = threadIdx.x;
  const int m0 = blockIdx.x * 64, n0 = blockIdx.y * 64;
  const int w = tid >> 6, lane = tid & 63;
  const int wm = (w & 1) * 32, wn = (w >> 1) * 32;
  const int fr = lane & 15, fg = lane >> 4;
  const int K = KF;

  f32x4 acc[2][2];
#pragma unroll
  for (int i = 0; i < 2; ++i)
#pragma unroll
    for (int j = 0; j < 2; ++j) acc[i][j] = (f32x4){0.f, 0.f, 0.f, 0.f};

  const int ar = tid >> 2, ak = (tid & 3) * 8;
  const ushort* ag = A + (size_t)(m0 + ar) * K + ak;
  const ushort* bg = Bt + (size_t)(n0 + ar) * K + ak;
  short8 a0 = *(const short8*)ag;
  short8 b0 = *(const short8*)bg;

  // prologue: stage tile 0 into buffer 0
  *(short8*)&As[0][ar][ak] = a0;
  *(short8*)&Bs[0][ar][ak] = b0;

  const int NT = K >> 5;
  for (int kt = 0; kt < NT; ++kt) {
    __syncthreads();
    const int cur = kt & 1, nxt = (kt + 1) & 1;
    if (kt + 1 < NT) {
      const size_t off = (size_t)(kt + 1) * 32;
      a0 = *(const short8*)(ag + off);
      b0 = *(const short8*)(bg + off);
    }
    short8 aF[2], bF[2];
#pragma unroll
    for (int i = 0; i < 2; ++i) aF[i] = *(const short8*)&As[cur][wm + i * 16 + fr][fg * 8];
#pragma unroll
    for (int j = 0; j < 2; ++j) bF[j] = *(const short8*)&Bs[cur][wn + j * 16 + fr][fg * 8];
#pragma unroll
    for (int i = 0; i < 2; ++i)
#pragma unroll
      for (int j = 0; j < 2; ++j)
        acc[i][j] = MFMA(aF[i], bF[j], acc[i][j]);
    if (kt + 1 < NT) {
      *(short8*)&As[nxt][ar][ak] = a0;
      *(short8*)&Bs[nxt][ar][ak] = b0;
    }
  }

  const int rb = fg * 4;
#pragma unroll
  for (int j = 0; j < 2; ++j) {
    const int n = n0 + wn + j * 16 + fr;
    const float bias = b_vo[n] + b_ao[n];
#pragma unroll
    for (int i = 0; i < 2; ++i)
#pragma unroll
      for (int r = 0; r < 4; ++r) {
        const int m = m0 + wm + i * 16 + rb + r;
        out[(size_t)m * ND + n] = acc[i][j][r] + bias;
      }
  }
}

// ---------------------------------------------------------------- k_stage
__global__ __launch_bounds__(256) void k_stage(
    const float* __restrict__ Y,
    const float* __restrict__ rots, const float* __restrict__ trans,
    const float* __restrict__ mask,
    const float* __restrict__ bvq, const float* __restrict__ bvk,
    const float* __restrict__ bvv, const float* __restrict__ baq,
    const float* __restrict__ bav,
    ushort* __restrict__ qAh, ushort* __restrict__ kBh,
    ushort* __restrict__ Vt,
    float* __restrict__ aq_t, float* __restrict__ penc)
{
  __shared__ __align__(16) char sbuf[36864];
  const int tid = threadIdx.x;

  if (blockIdx.z == 0) {
    float (*t0)[65] = (float(*)[65])sbuf;
    float (*t1)[72] = (float(*)[72])(sbuf + 16640);
    const int l0 = blockIdx.x * 64, h = blockIdx.y;
    const int b = l0 >> 10, ll0 = l0 & 1023;
    const int bh = b * NH + h;
    const int rr = tid >> 6, cc = tid & 63;
    const float inv = powf(10000.f, -(float)(cc & ~1) / 64.f);
    const bool odd = (cc & 1) != 0;

    for (int p = 0; p < 16; ++p) {
      const int r = p * 4 + rr;
      t0[r][cc] = Y[(size_t)(l0 + r) * NCAT + h * 64 + cc];
    }
    __syncthreads();
    for (int p = 0; p < 16; ++p) {
      const int r = p * 4 + rr;
      float sv, cv;
      __sincosf((float)(ll0 + r) * inv, &sv, &cv);
      const float e = t0[r][cc & ~1], o = t0[r][(cc & ~1) + 1];
      const float val = (odd ? fmaf(e, sv, o * cv) : fmaf(e, cv, -o * sv)) * SCL_S;
      qAh[((size_t)bh * NL + ll0 + r) * 128 + cc] = f2bf(val);
    }
    __syncthreads();
    for (int p = 0; p < 16; ++p) {
      const int r = p * 4 + rr;
      t0[r][cc] = Y[(size_t)(l0 + r) * NCAT + 512 + h * 64 + cc];
    }
    __syncthreads();
    for (int p = 0; p < 16; ++p) {
      const int r = p * 4 + rr;
      float sv, cv;
      __sincosf((float)(ll0 + r) * inv, &sv, &cv);
      const float e = t0[r][cc & ~1], o = t0[r][(cc & ~1) + 1];
      const float val = odd ? fmaf(e, sv, o * cv) : fmaf(e, cv, -o * sv);
      kBh[((size_t)bh * NL + ll0 + r) * 128 + cc] = f2bf(val);
    }
    for (int p = 0; p < 16; ++p) {
      const int r = p * 4 + rr;
      t1[cc][r] = Y[(size_t)(l0 + r) * NCAT + 1024 + h * 64 + cc];
    }
    __syncthreads();
    for (int p = 0; p < 16; ++p) {
      const int hd = p * 4 + rr;
      Vt[((size_t)bh * 112 + hd) * NL + ll0 + cc] = f2bf(t1[hd][cc]);
    }
    for (int u = tid; u < 9 * 64; u += 256)
      Vt[((size_t)bh * 112 + 103 + (u >> 6)) * NL + ll0 + (u & 63)] = 0;
    return;
  }

  float (*ys)[912] = (float(*)[912])sbuf;
  const int bid = blockIdx.y * 32 + blockIdx.x;
  const int tb = bid * 8;
  const int b = tb >> 10;

  for (int t = 0; t < 8; ++t)
    for (int n = tid; n < 912; n += 256)
      ys[t][n] = Y[(size_t)(tb + t) * NCAT + 1536 + n];
  __syncthreads();

  for (int u = tid; u < 8 * 288; u += 256) {
    const int t = u / 288, n = u % 288;
    const int l = tb + t, ll = l & (NL - 1);
    const int c = n % 3, base = n - c;
    const int h = n / NV3, m = n % NV3;
    const float r0 = rots[(size_t)l * 9 + c * 3 + 0];
    const float r1 = rots[(size_t)l * 9 + c * 3 + 1];
    const float r2 = rots[(size_t)l * 9 + c * 3 + 2];
    const float vqv = (r0 * (ys[t][base] + bvq[base])
                     + r1 * (ys[t][base + 1] + bvq[base + 1])
                     + r2 * (ys[t][base + 2] + bvq[base + 2])) * SCL_V;
    const float vkv = r0 * (ys[t][288 + base] + bvk[base])
                    + r1 * (ys[t][289 + base] + bvk[base + 1])
                    + r2 * (ys[t][290 + base] + bvk[base + 2]);
    const float vvv = r0 * (ys[t][576 + base] + bvv[base])
                    + r1 * (ys[t][577 + base] + bvv[base + 1])
                    + r2 * (ys[t][578 + base] + bvv[base + 2]);
    const size_t row = ((size_t)(b * NH + h) * NL + ll) * 128 + 64 + m;
    qAh[row] = f2bf(vqv);
    kBh[row] = f2bf(vkv);
    Vt[((size_t)(b * NH + h) * 112 + 64 + m) * NL + ll] = f2bf(vvv);
  }
  for (int u = tid; u < 8 * 8 * 14; u += 256) {
    const int t = u / 112, rem = u % 112, h = rem / 14, k = rem % 14;
    const int ll = (tb + t) & (NL - 1);
    const size_t row = ((size_t)(b * NH + h) * NL + ll) * 128 + 100 + 2 * k;
    *(uint*)&qAh[row] = 0;
  }
  for (int u = tid; u < 64; u += 256) {
    const int t = u >> 3, h = u & 7;
    const int l = tb + t, ll = l & (NL - 1);
    const int base = h * 3;
    const size_t tok = (size_t)(b * NH + h) * NL + ll;
#pragma unroll
    for (int c = 0; c < 3; ++c) {
      const float aqv =
          rots[(size_t)l * 9 + c * 3 + 0] * (ys[t][864 + base] + baq[base])
        + rots[(size_t)l * 9 + c * 3 + 1] * (ys[t][865 + base] + baq[base + 1])
        + rots[(size_t)l * 9 + c * 3 + 2] * (ys[t][866 + base] + baq[base + 2])
        + trans[(size_t)l * 3 + c];
      aq_t[((size_t)(b * NH + h) * 3 + c) * NL + ll] = aqv;
    }
#pragma unroll
    for (int k = 0; k < 14; ++k)
      *(uint*)&kBh[tok * 128 + 100 + 2 * k] = 0;
  }
  for (int u = tid; u < 8 * 24; u += 256) {
    const int t = u / 24, n = u % 24;
    const int l = tb + t, ll = l & (NL - 1);
    const int c = n % 3, h = n / 3, base = h * 3;
    const float val = rots[(size_t)l * 9 + c * 3 + 0] * (ys[t][888 + base] + bav[base])
                    + rots[(size_t)l * 9 + c * 3 + 1] * (ys[t][889 + base] + bav[base + 1])
                    + rots[(size_t)l * 9 + c * 3 + 2] * (ys[t][890 + base] + bav[base + 2])
                    + trans[(size_t)l * 3 + c];
    Vt[((size_t)(b * NH + h) * 112 + 100 + c) * NL + ll] = f2bf(val);
  }
  for (int u = tid; u < 8; u += 256) {
    const int ll = (tb + u) & (NL - 1);
    penc[(size_t)b * NL + ll] = 1e6f * (1.0f - mask[(size_t)b * NL + ll]);
  }
}

// ---------------------------------------------------------------- k_attn
// 8-wave cooperative flash attention: 512 thr = 4 row-groups x 2 j-halves.
// Each iteration stages BOTH halves' 64-wide K/V/aq tiles; wave (rg,jh)
// computes its half. Fixed-max softmax -> cross-wave combine is plain sum.
// Grid 256 = 16 bh x 16 row-tiles (64 rows), XCD-swizzled; 8 waves/CU.
__global__ __launch_bounds__(512) void k_attn(
    const ushort* __restrict__ qAh,
    const ushort* __restrict__ kBh, const ushort* __restrict__ Vt,
    const float* __restrict__ aq_t, const float* __restrict__ penc,
    const float* __restrict__ rots, const float* __restrict__ trans,
    const float* __restrict__ affw,
    ushort* __restrict__ catb)
{
  __shared__ __align__(16) ushort Ks[2][64][136];
  __shared__ __align__(16) ushort Vs[2][112][72];
  __shared__ float Aqs[2][4][64];
  __shared__ __align__(16) char uni[28672];   // P_s (loop) / Opart (epilogue)
  __shared__ float lst[8][16];
  __shared__ float linv[4][16];

  ushort (*P_s)[16][72]   = (ushort(*)[16][72])uni;
  ushort (*Opart)[16][112] = (ushort(*)[16][112])uni;

  const int blk = blockIdx.x;
  const int bh  = (blk & 7) * 2 + (blk >> 7);
  const int i0  = ((blk >> 3) & 15) * 64;
  const int b = bh >> 3, h = bh & 7;
  const int tid = threadIdx.x;
  const int w = tid >> 6, lane = tid & 63;
  const int rg = w & 3, jh = w >> 2;
  const int fr = lane & 15, fg = lane >> 4;
  const int irow = i0 + rg * 16;

  const float spw = logf(1.0f + expf(affw[h]));

  short8 aQ[4];
  const size_t qrow = ((size_t)bh * NL + irow + fr) * 128;
#pragma unroll
  for (int ks = 0; ks < 4; ++ks)
    aQ[ks] = *(const short8*)&qAh[qrow + ks * 32 + fg * 8];

  const float* aqx = aq_t + (size_t)bh * 3 * NL;
  float ai0[4], ai1[4], ai2[4];
#pragma unroll
  for (int r_ = 0; r_ < 4; ++r_) {
    const int row = irow + fg * 4 + r_;
    ai0[r_] = aqx[row];
    ai1[r_] = aqx[NL + row];
    ai2[r_] = aqx[2 * NL + row];
  }

  float lsum[4] = {0.f, 0.f, 0.f, 0.f};
  f32x4 accO[7];
#pragma unroll
  for (int ct = 0; ct < 7; ++ct) accO[ct] = (f32x4){0.f, 0.f, 0.f, 0.f};

  // staging roles (512 threads stage 2 half-tiles per iteration)
  const int hk = tid >> 8, krow = (tid >> 2) & 63, kc0 = (tid & 3) * 32;
  const int hv = (tid < 448) ? tid / 224 : 0;
  const int vrem = (tid < 448) ? tid % 224 : 0;
  const int vrow = vrem >> 1, vc0 = (vrem & 1) * 32;
  const int au = tid - 448;                      // tid>=448: aq/pen (64 thr)
  const size_t kgb = (size_t)bh * NL * 128 + (size_t)(hk * 512 + krow) * 128 + kc0;
  const size_t vgb = ((size_t)bh * 112 + vrow) * NL + hv * 512 + vc0;

  short8 kp[4], vp[4];
  float ap[8];

  auto loadTile = [&](int t) {
#pragma unroll
    for (int k = 0; k < 4; ++k)
      kp[k] = *(const short8*)&kBh[kgb + (size_t)t * 64 * 128 + k * 8];
    if (tid < 448) {
#pragma unroll
      for (int k = 0; k < 4; ++k)
        vp[k] = *(const short8*)&Vt[vgb + t * 64 + k * 8];
    } else {
#pragma unroll
      for (int q = 0; q < 8; ++q) {
        const int idx = au * 8 + q;              // 0..511
        const int ha = idx >> 8, rem2 = idx & 255;
        const int c = rem2 >> 6, jj = rem2 & 63;
        const int j = ha * 512 + t * 64 + jj;
        ap[q] = (c < 3) ? aqx[c * NL + j]
                        : penc[(size_t)b * NL + j];
      }
    }
  };
  auto storeTile = [&]() {
#pragma unroll
    for (int k = 0; k < 4; ++k)
      *(short8*)&Ks[hk][krow][kc0 + k * 8] = kp[k];
    if (tid < 448) {
#pragma unroll
      for (int k = 0; k < 4; ++k)
        *(short8*)&Vs[hv][vrow][vc0 + k * 8] = vp[k];
    } else {
#pragma unroll
      for (int q = 0; q < 8; ++q) {
        const int idx = au * 8 + q;
        Aqs[idx >> 8][(idx & 255) >> 6][idx & 63] = ap[q];
      }
    }
  };

  loadTile(0);
  for (int t = 0; t < 8; ++t) {
    __syncthreads();
    storeTile();
    __syncthreads();
    if (t < 7) loadTile(t + 1);

    // QK from staged K (this wave's half)
    f32x4 accS[4];
#pragma unroll
    for (int ct = 0; ct < 4; ++ct) accS[ct] = (f32x4){0.f, 0.f, 0.f, 0.f};
#pragma unroll
    for (int ct = 0; ct < 4; ++ct) {
#pragma unroll
      for (int ks = 0; ks < 4; ++ks) {
        const short8 bh8 = *(const short8*)&Ks[jh][ct * 16 + fr][ks * 32 + fg * 8];
        accS[ct] = MFMA(aQ[ks], bh8, accS[ct]);
      }
    }

    // distances + penalty; P = exp(s - FIXM)
#pragma unroll
    for (int ct = 0; ct < 4; ++ct) {
      const int jj = ct * 16 + fr;
      const float aj0 = Aqs[jh][0][jj];
      const float aj1 = Aqs[jh][1][jj];
      const float aj2v = Aqs[jh][2][jj];
      const float pen = Aqs[jh][3][jj];
#pragma unroll
      for (int r_ = 0; r_ < 4; ++r_) {
        const float dx = ai0[r_] - aj0;
        const float dy = ai1[r_] - aj1;
        const float dz = ai2[r_] - aj2v;
        const float s = accS[ct][r_]
                      - spw * sqrtf(dx * dx + dy * dy + dz * dz) - pen;
        const float p = __expf(s - FIXM);
        accS[ct][r_] = p;
        lsum[r_] += p;
      }
    }

    // P tile (wave-private LDS)
#pragma unroll
    for (int ct = 0; ct < 4; ++ct)
#pragma unroll
      for (int r_ = 0; r_ < 4; ++r_)
        P_s[w][fg * 4 + r_][ct * 16 + fr] = f2bf(accS[ct][r_]);

    const short8 aP0 = *(const short8*)&P_s[w][fr][fg * 8];
    const short8 aP1 = *(const short8*)&P_s[w][fr][32 + fg * 8];
#pragma unroll
    for (int ct = 0; ct < 7; ++ct) {
      const short8 b0 = *(const short8*)&Vs[jh][ct * 16 + fr][fg * 8];
      const short8 b1 = *(const short8*)&Vs[jh][ct * 16 + fr][32 + fg * 8];
      f32x4 tacc = MFMA(aP0, b0, accO[ct]);
      accO[ct] = MFMA(aP1, b1, tacc);
    }
  }

  // reduce L across fr lanes
#pragma unroll
  for (int off = 1; off < 16; off <<= 1) {
#pragma unroll
    for (int r_ = 0; r_ < 4; ++r_) lsum[r_] += __shfl_xor(lsum[r_], off);
  }

  __syncthreads();   // all waves done with P_s before Opart overlays it

  // publish partials (bf16 O, fp32 L)
#pragma unroll
  for (int ct = 0; ct < 7; ++ct)
#pragma unroll
    for (int r_ = 0; r_ < 4; ++r_)
      Opart[w][fg * 4 + r_][ct * 16 + fr] = f2bf(accO[ct][r_]);
  if (fr == 0) {
#pragma unroll
    for (int r_ = 0; r_ < 4; ++r_) lst[w][fg * 4 + r_] = lsum[r_];
  }
  __syncthreads();

  if (tid < 64) {
    const int g = tid >> 4, row = tid & 15;
    linv[g][row] = 1.0f / (lst[g][row] + lst[g + 4][row]);
  }
  __syncthreads();

  // epilogue: sum-combine j-halves + rotations + catb writes
  auto comb = [&](int row, int d) -> float {
    const int g = row >> 4, r16 = row & 15;
    return (bf2f(Opart[g][r16][d]) + bf2f(Opart[g + 4][r16][d])) * linv[g][r16];
  };
  for (int u = tid; u < 64 * 103; u += 512) {
    const int lr = u / 103, d = u % 103;
    const int gi = i0 + lr;
    const size_t gl = (size_t)b * NL + gi;
    float val;
    int col;
    if (d < 64) {
      val = comb(lr, d);
      col = h * 64 + d;
    } else if (d < 100) {
      const int v3 = d - 64;
      const int n = v3 % 3;
      const int base = 64 + v3 - n;
      val = comb(lr, base)     * rots[gl * 9 + n]
          + comb(lr, base + 1) * rots[gl * 9 + 3 + n]
          + comb(lr, base + 2) * rots[gl * 9 + 6 + n];
      col = 512 + h * NV3 + v3;
    } else {
      const int n = d - 100;
      const float c0 = comb(lr, 100) - trans[gl * 3 + 0];
      const float c1 = comb(lr, 101) - trans[gl * 3 + 1];
      const float c2 = comb(lr, 102) - trans[gl * 3 + 2];
      val = c0 * rots[gl * 9 + n] + c1 * rots[gl * 9 + 3 + n] + c2 * rots[gl * 9 + 6 + n];
      col = 800 + h * 3 + n;
    }
    catb[gl * KF + col] = f2bf(val);
  }
  if (h == 0) {
    for (int u = tid; u < 64 * 8; u += 512)
      catb[((size_t)b * NL + i0 + (u >> 3)) * KF + 824 + (u & 7)] = 0;
  }
}

} // namespace

extern "C" void kernel_launch(void* const* d_in, const int* in_sizes, int n_in,
                              void* d_out, int out_size, void* d_ws, size_t ws_size,
                              hipStream_t stream)
{
  const float* x       = (const float*)d_in[0];
  const float* mask    = (const float*)d_in[1];
  const float* rots    = (const float*)d_in[2];
  const float* trans   = (const float*)d_in[3];
  const float* w_q     = (const float*)d_in[4];
  const float* w_k     = (const float*)d_in[5];
  const float* w_v     = (const float*)d_in[6];
  const float* w_o     = (const float*)d_in[7];
  const float* w_vq_w  = (const float*)d_in[8];
  const float* w_vq_b  = (const float*)d_in[9];
  const float* w_vk_w  = (const float*)d_in[10];
  const float* w_vk_b  = (const float*)d_in[11];
  const float* w_vv_w  = (const float*)d_in[12];
  const float* w_vv_b  = (const float*)d_in[13];
  const float* w_vo_w  = (const float*)d_in[14];
  const float* w_vo_b  = (const float*)d_in[15];
  const float* w_aq_w  = (const float*)d_in[16];
  const float* w_aq_b  = (const float*)d_in[17];
  const float* w_av_w  = (const float*)d_in[18];
  const float* w_av_b  = (const float*)d_in[19];
  const float* w_ao_w  = (const float*)d_in[20];
  const float* w_ao_b  = (const float*)d_in[21];
  const float* aff_w   = (const float*)d_in[22];
  float* out = (float*)d_out;

  char* base = (char*)d_ws;
  ushort* xh  = (ushort*)base;
  ushort* xl  = xh + (size_t)2048 * 512;
  ushort* wch = xl + (size_t)2048 * 512;
  ushort* qAh = (ushort*)base;                       // 4 MB (over xh+xl)
  float*  aq_t = (float*)(wch + (size_t)2560 * 512); // 196 KB (after wch)
  char* p = base + 9437184;
  ushort* wcat2 = (ushort*)p; p += (size_t)512 * 832 * 2;
  float*  Y     = (float*)p;
  ushort* catb  = (ushort*)Y;
  p += (size_t)2048 * 2560 * 4;
  ushort* kBh = (ushort*)p; p += (size_t)16 * 1024 * 128 * 2;
  ushort* Vt  = (ushort*)p; p += (size_t)16 * 112 * 1024 * 2;
  float* penc = (float*)p;  p += (size_t)2048 * 4;

  k_wprep<<<dim3(40, 13, 3), 256, 0, stream>>>(w_q, w_k, w_v, w_vq_w, w_vk_w,
                                               w_vv_w, w_aq_w, w_av_w,
                                               w_o, w_vo_w, w_ao_w, x,
                                               wch, wcat2, xh, xl);
  k_mm<<<dim3(16, 40), 256, 0, stream>>>(xh, xl, wch, Y, NCAT, 512);
  k_stage<<<dim3(32, 8, 2), 256, 0, stream>>>(Y, rots, trans, mask,
                                              w_vq_b, w_vk_b, w_vv_b,
                                              w_aq_b, w_av_b,
                                              qAh, kBh, Vt, aq_t, penc);
  k_attn<<<256, 512, 0, stream>>>(qAh, kBh, Vt,
                                  aq_t, penc, rots, trans, aff_w, catb);
  k_fin<<<dim3(32, 8), 256, 0, stream>>>(catb, wcat2, w_vo_b, w_ao_b, out);
}